// Round 26
// baseline (437.436 us; speedup 1.0000x reference)
//
#include <hip/hip_runtime.h>

typedef unsigned short ushort_t;
typedef __attribute__((ext_vector_type(8))) short short8;
typedef __attribute__((ext_vector_type(4))) float f32x4;
typedef __attribute__((ext_vector_type(4))) unsigned short bf4;
typedef __attribute__((ext_vector_type(8))) unsigned short bf8v;

__device__ __forceinline__ ushort_t f2bf(float f) {
    union { float f; unsigned u; } v; v.f = f;
    unsigned r = v.u + 0x7FFFu + ((v.u >> 16) & 1u);
    return (ushort_t)(r >> 16);
}

__device__ __forceinline__ void g2lds16(const ushort_t* g, ushort_t* l) {
    __builtin_amdgcn_global_load_lds(
        (const __attribute__((address_space(1))) void*)g,
        (__attribute__((address_space(3))) void*)l, 16, 0, 0);
}

#define LDT 72  // padded LDS row stride (reg-staged paths)

// ---------------------------------------------------------------------------
// gemm_big: logits GEMM (r14 structure + r17 fused text-gather in A-staging).
// Best-validated form: dbuf + counted vmcnt(8), monolithic MFMA block.
// ---------------------------------------------------------------------------
__global__ __launch_bounds__(512) void gemm_big(
    const ushort_t* __restrict__ xb, const ushort_t* __restrict__ B,
    float* __restrict__ C, const float* __restrict__ bias,
    int K, int ldb, int ldc, int validM)
{
    __shared__ __attribute__((aligned(16))) ushort_t As[2][256 * 64];
    __shared__ __attribute__((aligned(16))) ushort_t Bs[2][256 * 64];

    const int tid = threadIdx.x;
    const int lane = tid & 63;
    const int wave = tid >> 6;       // 0..7
    const int wr = wave >> 2;        // 0..1 : 128-row band
    const int wc = wave & 3;         // 0..3 : 64-col slice
    int tN, tM;
    {
        const int lin = blockIdx.x + blockIdx.y * gridDim.x;
        const int TM = gridDim.y;
        const int full = gridDim.x >> 3;
        const int per = TM << 3;
        const int g = lin / per;
        if (g < full) {
            const int rem = lin - g * per;
            tM = rem >> 3;
            tN = (g << 3) + (rem & 7);
        } else {
            const int rem = lin - full * per;
            const int w = gridDim.x - (full << 3);
            tM = rem / w;
            tN = (full << 3) + rem - tM * w;
        }
    }
    const int n0 = tN * 256;
    const ushort_t* Bbase = B + (long)n0 * ldb;

    f32x4 acc[8][4];
#pragma unroll
    for (int m = 0; m < 8; m++)
#pragma unroll
        for (int n = 0; n < 4; n++) acc[m][n] = (f32x4)0.f;

    auto STAGE = [&](int buf, int ks) {
#pragma unroll
        for (int i = 0; i < 4; i++) {
            int ch = i * 512 + tid;
            int row = ch >> 3, c16 = ch & 7;
            int c16s = c16 ^ (row & 7);
            int gr = tM * 256 + row;
            if (gr > 2431) gr = 2431;            // masked by validM at store
            int bb = gr / 76;
            int xrow = bb * 126 + 50 + (gr - bb * 76);
            g2lds16(xb + (long)xrow * 512 + ks + (c16s << 3),
                    &As[buf][(i * 512 + wave * 64) * 8]);
        }
#pragma unroll
        for (int i = 0; i < 4; i++) {
            int ch = i * 512 + tid;
            int row = ch >> 3, c16 = ch & 7;
            int c16s = c16 ^ (row & 7);
            g2lds16(Bbase + (long)row * ldb + ks + (c16s << 3),
                    &Bs[buf][(i * 512 + wave * 64) * 8]);
        }
    };

    const int nt = K >> 6;
    STAGE(0, 0);
    for (int t = 0; t < nt; ++t) {
        if (t + 1 < nt) {
            STAGE((t + 1) & 1, (t + 1) << 6);
            asm volatile("s_waitcnt vmcnt(8)" ::: "memory");   // tile t done
        } else {
            asm volatile("s_waitcnt vmcnt(0)" ::: "memory");
        }
        asm volatile("s_barrier" ::: "memory");

        const ushort_t* Ac = As[t & 1];
        const ushort_t* Bc = Bs[t & 1];
        __builtin_amdgcn_s_setprio(1);
#pragma unroll
        for (int ksub = 0; ksub < 2; ksub++) {
            const int kk = ksub * 32 + ((lane >> 4) << 3);
            const int kc = kk >> 3;
            short8 af[8], bfr[4];
#pragma unroll
            for (int m = 0; m < 8; m++) {
                const int r = (wr << 7) + m * 16 + (lane & 15);
                af[m] = *(const short8*)(Ac + r * 64 + ((kc ^ (r & 7)) << 3));
            }
#pragma unroll
            for (int n = 0; n < 4; n++) {
                const int r = (wc << 6) + n * 16 + (lane & 15);
                bfr[n] = *(const short8*)(Bc + r * 64 + ((kc ^ (r & 7)) << 3));
            }
#pragma unroll
            for (int m = 0; m < 8; m++)
#pragma unroll
                for (int n = 0; n < 4; n++)
                    acc[m][n] = __builtin_amdgcn_mfma_f32_16x16x32_bf16(
                        af[m], bfr[n], acc[m][n], 0, 0, 0);
        }
        __builtin_amdgcn_s_setprio(0);
        asm volatile("s_barrier" ::: "memory");
    }

    const int rb = (wr << 7) + ((lane >> 4) << 2);
    const int cb = (wc << 6) + (lane & 15);
#pragma unroll
    for (int m = 0; m < 8; m++) {
#pragma unroll
        for (int i = 0; i < 4; i++) {
            int r = tM * 256 + rb + m * 16 + i;
            if (r >= validM) continue;
#pragma unroll
            for (int n = 0; n < 4; n++) {
                int cg = n0 + cb + n * 16;
                C[(long)r * ldc + cg] = acc[m][n][i] + bias[cg];
            }
        }
    }
}

// ---------------------------------------------------------------------------
// ff1_fused: y = LN(x + xb@ff1T^T + ff1_b) in place (r20, validated).
// ---------------------------------------------------------------------------
__global__ __launch_bounds__(512) void ff1_fused(
    ushort_t* __restrict__ xbg, const ushort_t* __restrict__ ff1T,
    const float* __restrict__ bias, float* __restrict__ xg,
    const float* __restrict__ ln_g, const float* __restrict__ ln_b)
{
    __shared__ __attribute__((aligned(16))) ushort_t As[32 * 64];    // 4 KB
    __shared__ __attribute__((aligned(16))) ushort_t Bs[512 * 64];   // 64 KB
    __shared__ float redm[4 * 32];
    __shared__ float reds[4 * 32];

    const int tid = threadIdx.x;
    const int lane = tid & 63;
    const int wave = tid >> 6;
    const int wr = wave >> 2;     // 0..1 : 16-row band
    const int wc = wave & 3;      // 0..3 : 128-col slice
    const int r0 = blockIdx.x << 5;   // 32 rows/block, 126 blocks, all valid

    f32x4 acc[8];
#pragma unroll
    for (int n = 0; n < 8; n++) acc[n] = (f32x4)0.f;

    auto STAGE = [&](int ks) {
        // chunk space: A = 256 chunks (32x64), B = 4096 chunks (512x64)
#pragma unroll
        for (int i = 0; i < 9; i++) {
            int cb = i * 512 + wave * 64;       // wave-uniform chunk base
            if (cb >= 4352) continue;
            int ch = cb + lane;
            if (cb < 256) {                     // A chunk
                int row = ch >> 3, c16 = ch & 7;
                int c16s = c16 ^ (row & 7);
                g2lds16(xbg + (long)(r0 + row) * 512 + ks + (c16s << 3),
                        &As[cb * 8]);
            } else {                            // B chunk
                int bch = ch - 256;
                int row = bch >> 3, c16 = bch & 7;
                int c16s = c16 ^ (row & 7);
                g2lds16(ff1T + (long)row * 512 + ks + (c16s << 3),
                        &Bs[(cb - 256) * 8]);
            }
        }
    };

    for (int ks = 0; ks < 512; ks += 64) {
        if (ks) asm volatile("s_barrier" ::: "memory");  // prev readers done
        STAGE(ks);
        asm volatile("s_waitcnt vmcnt(0)" ::: "memory");
        asm volatile("s_barrier" ::: "memory");

        __builtin_amdgcn_s_setprio(1);
#pragma unroll
        for (int ksub = 0; ksub < 2; ksub++) {
            const int kc = ksub * 4 + (lane >> 4);
            short8 af;
            {
                const int r = (wr << 4) + (lane & 15);
                af = *(const short8*)(As + r * 64 + ((kc ^ (r & 7)) << 3));
            }
            short8 bfr[8];
#pragma unroll
            for (int n = 0; n < 8; n++) {
                const int r = (wc << 7) + n * 16 + (lane & 15);
                bfr[n] = *(const short8*)(Bs + r * 64 + ((kc ^ (r & 7)) << 3));
            }
#pragma unroll
            for (int n = 0; n < 8; n++)
                acc[n] = __builtin_amdgcn_mfma_f32_16x16x32_bf16(
                    af, bfr[n], acc[n], 0, 0, 0);
        }
        __builtin_amdgcn_s_setprio(0);
    }

    // ---- epilogue: bias + residual + LayerNorm ----
    float gg[8], bb2[8], bi[8];
#pragma unroll
    for (int n = 0; n < 8; n++) {
        int d = (wc << 7) + n * 16 + (lane & 15);
        gg[n] = ln_g[d];
        bb2[n] = ln_b[d];
        bi[n] = bias[d];
    }
    float vv[4][8];
#pragma unroll
    for (int i = 0; i < 4; i++) {
        const int rl = (wr << 4) + ((lane >> 4) << 2) + i;
        const long xrow = (long)(r0 + rl) << 9;
        float s = 0.f, sq = 0.f;
#pragma unroll
        for (int n = 0; n < 8; n++) {
            int d = (wc << 7) + n * 16 + (lane & 15);
            float v = acc[n][i] + bi[n] + xg[xrow + d];
            vv[i][n] = v;
            s += v; sq += v * v;
        }
#pragma unroll
        for (int o = 8; o >= 1; o >>= 1) { s += __shfl_xor(s, o); sq += __shfl_xor(sq, o); }
        if ((lane & 15) == 0) {
            redm[wc * 32 + rl] = s;
            reds[wc * 32 + rl] = sq;
        }
    }
    __syncthreads();
#pragma unroll
    for (int i = 0; i < 4; i++) {
        const int rl = (wr << 4) + ((lane >> 4) << 2) + i;
        float S = redm[rl] + redm[32 + rl] + redm[64 + rl] + redm[96 + rl];
        float SQ = reds[rl] + reds[32 + rl] + reds[64 + rl] + reds[96 + rl];
        float mean = S * (1.f / 512.f);
        float var = SQ * (1.f / 512.f) - mean * mean;
        float inv = rsqrtf(var + 1e-5f);
        const long xrow = (long)(r0 + rl) << 9;
#pragma unroll
        for (int n = 0; n < 8; n++) {
            int d = (wc << 7) + n * 16 + (lane & 15);
            float y = (vv[i][n] - mean) * inv * gg[n] + bb2[n];
            xg[xrow + d] = y;
            xbg[xrow + d] = f2bf(y);
        }
    }
}

// ---------------------------------------------------------------------------
// attn_fused: QK^T + softmax + PV + residual-LN (r18, validated).
// ---------------------------------------------------------------------------
__global__ __launch_bounds__(512) void attn_fused(
    const ushort_t* __restrict__ qkv, float* __restrict__ xg,
    ushort_t* __restrict__ xbg, const float* __restrict__ ln_g,
    const float* __restrict__ ln_b)
{
    __shared__ __attribute__((aligned(16))) ushort_t smem[41984];
    ushort_t* Vs = smem;                      // [512][64]   (phase 3)
    ushort_t* Ps = smem + 32768;              // [64][128]
    float* redm = (float*)(smem + 40960);     // [4][64]
    float* reds = redm + 256;                 // [4][64]
    ushort_t* Qs = smem;                      // [2][64*64]  (phase 1)
    ushort_t* Ks = smem + 8192;               // [2][128*64]

    const int tid = threadIdx.x;
    const int lane = tid & 63;
    const int wave = tid >> 6;
    const int wr = wave >> 2;     // 0..1
    const int wc = wave & 3;      // 0..3
    const int qh = blockIdx.x;    // 0..1
    const int b  = blockIdx.y;    // 0..31
    const long qbase = ((long)(b * 126) + qh * 64) * 1536;
    const long kbase = (long)(b * 126) * 1536 + 512;
    const long vbase = (long)(b * 126) * 1536 + 1024;
    const float rsqd = 0.044194173824159216f;

    // ================= phase 1: S = Q K^T =================
    f32x4 acc[2][2];
#pragma unroll
    for (int m = 0; m < 2; m++)
#pragma unroll
        for (int n = 0; n < 2; n++) acc[m][n] = (f32x4)0.f;

    auto SQK = [&](int buf, int ks) {
        {   // Q tile 64x64: 512 chunks, 1/thread
            int ch = tid;
            int row = ch >> 3, c16 = ch & 7;
            int c16s = c16 ^ (row & 7);
            g2lds16(qkv + qbase + (long)row * 1536 + ks + (c16s << 3),
                    Qs + buf * 4096 + (wave * 64) * 8);
        }
#pragma unroll
        for (int i = 0; i < 2; i++) {  // K tile 128x64: 1024 chunks
            int ch = i * 512 + tid;
            int row = ch >> 3, c16 = ch & 7;
            int c16s = c16 ^ (row & 7);
            g2lds16(qkv + kbase + (long)row * 1536 + ks + (c16s << 3),
                    Ks + buf * 8192 + (i * 512 + wave * 64) * 8);
        }
    };

    SQK(0, 0);
    for (int t = 0; t < 8; ++t) {
        if (t < 7) {
            SQK((t + 1) & 1, (t + 1) << 6);
            asm volatile("s_waitcnt vmcnt(3)" ::: "memory");
        } else {
            asm volatile("s_waitcnt vmcnt(0)" ::: "memory");
        }
        asm volatile("s_barrier" ::: "memory");
        const ushort_t* Qc = Qs + (t & 1) * 4096;
        const ushort_t* Kc = Ks + (t & 1) * 8192;
#pragma unroll
        for (int ksub = 0; ksub < 2; ksub++) {
            const int kc = ksub * 4 + (lane >> 4);
            short8 af[2], bfr[2];
#pragma unroll
            for (int m = 0; m < 2; m++) {
                const int r = (wr << 5) + m * 16 + (lane & 15);
                af[m] = *(const short8*)(Qc + r * 64 + ((kc ^ (r & 7)) << 3));
            }
#pragma unroll
            for (int n = 0; n < 2; n++) {
                const int r = (wc << 5) + n * 16 + (lane & 15);
                bfr[n] = *(const short8*)(Kc + r * 64 + ((kc ^ (r & 7)) << 3));
            }
#pragma unroll
            for (int m = 0; m < 2; m++)
#pragma unroll
                for (int n = 0; n < 2; n++)
                    acc[m][n] = __builtin_amdgcn_mfma_f32_16x16x32_bf16(
                        af[m], bfr[n], acc[m][n], 0, 0, 0);
        }
        asm volatile("s_barrier" ::: "memory");
    }

    // ================= phase 2: masked softmax =================
    float rm[2][4];
#pragma unroll
    for (int m = 0; m < 2; m++) {
#pragma unroll
        for (int i = 0; i < 4; i++) {
            const int rl = (wr << 5) + m * 16 + ((lane >> 4) << 2) + i;
            const int q = qh * 64 + rl;
            float mx = -3.0e38f;
#pragma unroll
            for (int n = 0; n < 2; n++) {
                int j = (wc << 5) + n * 16 + (lane & 15);
                bool ok = (j < 126) && ((j < 50) || (j <= q));
                float s = acc[m][n][i] * rsqd;
                acc[m][n][i] = ok ? s : -3.0e38f;
                if (ok) mx = fmaxf(mx, s);
            }
#pragma unroll
            for (int o = 8; o >= 1; o >>= 1) mx = fmaxf(mx, __shfl_xor(mx, o));
            rm[m][i] = mx;
        }
    }
    if ((lane & 15) == 0) {
#pragma unroll
        for (int m = 0; m < 2; m++)
#pragma unroll
            for (int i = 0; i < 4; i++) {
                int rl = (wr << 5) + m * 16 + ((lane >> 4) << 2) + i;
                redm[wc * 64 + rl] = rm[m][i];
            }
    }
    __syncthreads();
    float rs[2][4];
#pragma unroll
    for (int m = 0; m < 2; m++) {
#pragma unroll
        for (int i = 0; i < 4; i++) {
            const int rl = (wr << 5) + m * 16 + ((lane >> 4) << 2) + i;
            float M = fmaxf(fmaxf(redm[rl], redm[64 + rl]),
                            fmaxf(redm[128 + rl], redm[192 + rl]));
            float sum = 0.f;
#pragma unroll
            for (int n = 0; n < 2; n++) {
                float s = acc[m][n][i];
                float e = (s > -1.0e37f) ? expf(s - M) : 0.f;
                acc[m][n][i] = e;
                sum += e;
            }
#pragma unroll
            for (int o = 8; o >= 1; o >>= 1) sum += __shfl_xor(sum, o);
            rs[m][i] = sum;
        }
    }
    if ((lane & 15) == 0) {
#pragma unroll
        for (int m = 0; m < 2; m++)
#pragma unroll
            for (int i = 0; i < 4; i++) {
                int rl = (wr << 5) + m * 16 + ((lane >> 4) << 2) + i;
                reds[wc * 64 + rl] = rs[m][i];
            }
    }
    __syncthreads();
#pragma unroll
    for (int m = 0; m < 2; m++) {
#pragma unroll
        for (int i = 0; i < 4; i++) {
            const int rl = (wr << 5) + m * 16 + ((lane >> 4) << 2) + i;
            float S = reds[rl] + reds[64 + rl] + reds[128 + rl] + reds[192 + rl];
            float inv = 1.f / S;
#pragma unroll
            for (int n = 0; n < 2; n++) {
                int j = (wc << 5) + n * 16 + (lane & 15);
                int c = j >> 3;
                Ps[rl * 128 + ((c ^ (rl & 7)) << 3) + (j & 7)] =
                    f2bf(acc[m][n][i] * inv);
            }
        }
    }
    __syncthreads();

    // ================= phase 3: attn = P V =================
    f32x4 po[2][8];
#pragma unroll
    for (int m = 0; m < 2; m++)
#pragma unroll
        for (int n = 0; n < 8; n++) po[m][n] = (f32x4)0.f;

    for (int jc = 0; jc < 2; jc++) {
#pragma unroll
        for (int q8 = 0; q8 < 16; q8++) {
            int qid = q8 * 512 + tid;           // 0..8191
            int d = qid & 511, jq = qid >> 9;   // jq 0..15
            const ushort_t* vp = qkv + vbase + (long)(jc * 64 + jq * 4) * 1536 + d;
            bf4 p;
            p[0] = vp[0];
            p[1] = vp[1536];
            p[2] = vp[3072];
            p[3] = vp[4608];
            *(bf4*)(Vs + d * 64 + (((jq >> 1) ^ (d & 7)) << 3) + ((jq & 1) << 2)) = p;
        }
        __syncthreads();
#pragma unroll
        for (int ksub = 0; ksub < 2; ksub++) {
            const int kc = ksub * 4 + (lane >> 4);
            short8 af[2], bv[8];
#pragma unroll
            for (int m = 0; m < 2; m++) {
                const int r = (wr << 5) + m * 16 + (lane & 15);
                const int c = jc * 8 + kc;
                af[m] = *(const short8*)(Ps + r * 128 + ((c ^ (r & 7)) << 3));
            }
#pragma unroll
            for (int n = 0; n < 8; n++) {
                const int r = (wc << 7) + n * 16 + (lane & 15);
                bv[n] = *(const short8*)(Vs + r * 64 + ((kc ^ (r & 7)) << 3));
            }
#pragma unroll
            for (int m = 0; m < 2; m++)
#pragma unroll
                for (int n = 0; n < 8; n++)
                    po[m][n] = __builtin_amdgcn_mfma_f32_16x16x32_bf16(
                        af[m], bv[n], po[m][n], 0, 0, 0);
        }
        __syncthreads();
    }

    // ========= phase 4: residual + LayerNorm -> x, xb =========
    float gg[8], bb2[8];
#pragma unroll
    for (int n = 0; n < 8; n++) {
        int d = (wc << 7) + n * 16 + (lane & 15);
        gg[n] = ln_g[d];
        bb2[n] = ln_b[d];
    }
#pragma unroll
    for (int m = 0; m < 2; m++) {
#pragma unroll
        for (int i = 0; i < 4; i++) {
            const int rl = (wr << 5) + m * 16 + ((lane >> 4) << 2) + i;
            const int q = qh * 64 + rl;
            const long xrow = ((long)(b * 126 + q)) << 9;   // q>=126: pad row, zeroed
            float s = 0.f, sq = 0.f;
#pragma unroll
            for (int n = 0; n < 8; n++) {
                int d = (wc << 7) + n * 16 + (lane & 15);
                float v = po[m][n][i] + xg[xrow + d];
                po[m][n][i] = v;
                s += v; sq += v * v;
            }
#pragma unroll
            for (int o = 8; o >= 1; o >>= 1) { s += __shfl_xor(s, o); sq += __shfl_xor(sq, o); }
            if ((lane & 15) == 0) {
                redm[wc * 64 + rl] = s;
                reds[wc * 64 + rl] = sq;
            }
        }
    }
    __syncthreads();
#pragma unroll
    for (int m = 0; m < 2; m++) {
#pragma unroll
        for (int i = 0; i < 4; i++) {
            const int rl = (wr << 5) + m * 16 + ((lane >> 4) << 2) + i;
            const int q = qh * 64 + rl;
            if (q >= 126) continue;
            float S = redm[rl] + redm[64 + rl] + redm[128 + rl] + redm[192 + rl];
            float SQ = reds[rl] + reds[64 + rl] + reds[128 + rl] + reds[192 + rl];
            float mean = S * (1.f / 512.f);
            float var = SQ * (1.f / 512.f) - mean * mean;
            float inv = rsqrtf(var + 1e-5f);
            const long xrow = ((long)(b * 126 + q)) << 9;
#pragma unroll
            for (int n = 0; n < 8; n++) {
                int d = (wc << 7) + n * 16 + (lane & 15);
                float y = (po[m][n][i] - mean) * inv * gg[n] + bb2[n];
                xg[xrow + d] = y;
                xbg[xrow + d] = f2bf(y);
            }
        }
    }
}

// ---------------------------------------------------------------------------
// Batched bf16 GEMM (128x128): BSRC=0 dbuf + counted vmcnt; BSRC=1 reg-staged
// fallback (validated).
// ---------------------------------------------------------------------------
template <int BSRC, int SWZ, int NT>
__global__ __launch_bounds__(256) void gemm_bf16(
    const ushort_t* __restrict__ A, const void* __restrict__ Bv,
    float* __restrict__ C, ushort_t* __restrict__ Cb,
    const float* __restrict__ bias,
    int K, int lda, int ldb, int ldc,
    long sA, long sB, long sC,
    int validM, float scale)
{
    constexpr int LS = (BSRC == 0) ? 64 : LDT;
    constexpr int NBUF = (BSRC == 0) ? 2 : 1;
    __shared__ __attribute__((aligned(16))) ushort_t As[NBUF * 128 * LS];
    __shared__ __attribute__((aligned(16))) ushort_t Bs[NBUF * 128 * LS];

    const int tid = threadIdx.x;
    const int lane = tid & 63;
    const int wave = tid >> 6;
    const int wr = wave >> 1, wc = wave & 1;
    int tN = blockIdx.x, tM = blockIdx.y;
    const int bz = blockIdx.z;
    if (SWZ) {
        const int lin = blockIdx.x + blockIdx.y * gridDim.x;
        const int TM = gridDim.y;
        const int full = gridDim.x >> 3;
        const int per = TM << 3;
        const int g = lin / per;
        if (g < full) {
            const int rem = lin - g * per;
            tM = rem >> 3;
            tN = (g << 3) + (rem & 7);
        } else {
            const int rem = lin - full * per;
            const int w = gridDim.x - (full << 3);
            tM = rem / w;
            tN = (full << 3) + rem - tM * w;
        }
    }
    const int n0 = tN * 128;

    const ushort_t* Abase = A + (long)bz * sA + (long)tM * 128 * lda;
    const ushort_t* Bb = (BSRC == 0)
        ? (const ushort_t*)Bv + (long)bz * sB + (long)n0 * ldb : nullptr;
    const float* Bf = (BSRC == 1)
        ? (const float*)Bv + (long)bz * sB : nullptr;

    f32x4 acc[4][4];
#pragma unroll
    for (int m = 0; m < 4; m++)
#pragma unroll
        for (int n = 0; n < 4; n++) acc[m][n] = (f32x4)0.f;

    if (BSRC == 0) {
        auto STAGE = [&](int buf, int ks) {
            ushort_t* Ad = As + buf * (128 * 64);
            ushort_t* Bd = Bs + buf * (128 * 64);
#pragma unroll
            for (int i = 0; i < 4; i++) {
                int ch = wave * 256 + i * 64 + lane;
                int row = ch >> 3, c16 = ch & 7;
                int c16s = c16 ^ (row & 7);
                g2lds16(Abase + (long)row * lda + ks + (c16s << 3),
                        Ad + (wave * 256 + i * 64) * 8);
            }
#pragma unroll
            for (int i = 0; i < 4; i++) {
                int ch = wave * 256 + i * 64 + lane;
                int row = ch >> 3, c16 = ch & 7;
                int c16s = c16 ^ (row & 7);
                g2lds16(Bb + (long)row * ldb + ks + (c16s << 3),
                        Bd + (wave * 256 + i * 64) * 8);
            }
        };

        const int nt = K >> 6;
        STAGE(0, 0);
        for (int t = 0; t < nt; ++t) {
            if (t + 1 < nt) {
                STAGE((t + 1) & 1, (t + 1) << 6);
                asm volatile("s_waitcnt vmcnt(8)" ::: "memory");
            } else {
                asm volatile("s_waitcnt vmcnt(0)" ::: "memory");
            }
            asm volatile("s_barrier" ::: "memory");

            const ushort_t* Ac = As + (t & 1) * (128 * 64);
            const ushort_t* Bc = Bs + (t & 1) * (128 * 64);
#pragma unroll
            for (int ksub = 0; ksub < 2; ksub++) {
                const int kk = ksub * 32 + ((lane >> 4) << 3);
                const int kc = kk >> 3;
                short8 af[4], bfr[4];
#pragma unroll
                for (int m = 0; m < 4; m++) {
                    const int r = (wr << 6) + m * 16 + (lane & 15);
                    af[m] = *(const short8*)(Ac + r * 64 + ((kc ^ (r & 7)) << 3));
                }
#pragma unroll
                for (int n = 0; n < 4; n++) {
                    const int r = (wc << 6) + n * 16 + (lane & 15);
                    bfr[n] = *(const short8*)(Bc + r * 64 + ((kc ^ (r & 7)) << 3));
                }
#pragma unroll
                for (int m = 0; m < 4; m++)
#pragma unroll
                    for (int n = 0; n < 4; n++)
                        acc[m][n] = __builtin_amdgcn_mfma_f32_16x16x32_bf16(
                            af[m], bfr[n], acc[m][n], 0, 0, 0);
            }
            asm volatile("s_barrier" ::: "memory");
        }
    } else {
        for (int ks = 0; ks < K; ks += 64) {
            short8 ar[4];
#pragma unroll
            for (int i = 0; i < 4; i++) {
                int ch = wave * 256 + i * 64 + lane;
                int row = ch >> 3, c16 = ch & 7;
                ar[i] = *(const short8*)(Abase + (long)row * lda + ks + (c16 << 3));
            }
            bf4 pk[8];
#pragma unroll
            for (int q = 0; q < 8; q++) {
                int qid = q * 256 + tid;
                int n = qid & 127, kq = qid >> 7;
                const float* wp = Bf + (long)(ks + kq * 4) * ldb + n0 + n;
                bf4 p;
                p[0] = f2bf(wp[0]);
                p[1] = f2bf(wp[ldb]);
                p[2] = f2bf(wp[2 * (long)ldb]);
                p[3] = f2bf(wp[3 * (long)ldb]);
                pk[q] = p;
            }
            if (ks) __syncthreads();
#pragma unroll
            for (int i = 0; i < 4; i++) {
                int ch = wave * 256 + i * 64 + lane;
                int row = ch >> 3, c16 = ch & 7;
                *(short8*)(As + row * LS + (c16 << 3)) = ar[i];
            }
#pragma unroll
            for (int q = 0; q < 8; q++) {
                int qid = q * 256 + tid;
                int n = qid & 127, kq = qid >> 7;
                *(bf4*)(Bs + n * LS + (kq << 2)) = pk[q];
            }
            __syncthreads();

#pragma unroll
            for (int ksub = 0; ksub < 2; ksub++) {
                const int kk = ksub * 32 + ((lane >> 4) << 3);
                short8 af[4], bfr[4];
#pragma unroll
                for (int m = 0; m < 4; m++) {
                    const int r = (wr << 6) + m * 16 + (lane & 15);
                    af[m] = *(const short8*)(As + r * LS + kk);
                }
#pragma unroll
                for (int n = 0; n < 4; n++) {
                    const int r = (wc << 6) + n * 16 + (lane & 15);
                    bfr[n] = *(const short8*)(Bs + r * LS + kk);
                }
#pragma unroll
                for (int m = 0; m < 4; m++)
#pragma unroll
                    for (int n = 0; n < 4; n++)
                        acc[m][n] = __builtin_amdgcn_mfma_f32_16x16x32_bf16(
                            af[m], bfr[n], acc[m][n], 0, 0, 0);
            }
            if (ks + 64 < K) __syncthreads();
        }
    }

    const int rb = (wr << 6) + ((lane >> 4) << 2);
    const int cb = (wc << 6) + (lane & 15);
#pragma unroll
    for (int m = 0; m < 4; m++) {
#pragma unroll
        for (int i = 0; i < 4; i++) {
            int r = tM * 128 + rb + m * 16 + i;
            if (r >= validM) continue;
#pragma unroll
            for (int n = 0; n < 4; n++) {
                int cg = n0 + cb + n * 16;
                float v = acc[m][n][i] * scale + (bias ? bias[cg] : 0.f);
                long off = (long)bz * sC + (long)r * ldc + cg;
                if (C) {
                    if (NT) __builtin_nontemporal_store(v, &C[off]);
                    else    C[off] = v;
                }
                if (Cb) Cb[off] = f2bf(v);
            }
        }
    }
}

// ---------------------------------------------------------------------------
// transpose f32 [R][C] -> bf16 [C][R]   (small weights)
// ---------------------------------------------------------------------------
__global__ __launch_bounds__(256) void transpose_bf(
    const float* __restrict__ in, ushort_t* __restrict__ out, int R, int C)
{
    __shared__ float t[32][33];
    int c0 = blockIdx.x << 5, r0 = blockIdx.y << 5;
    int tx = threadIdx.x, ty = threadIdx.y;
#pragma unroll
    for (int i = 0; i < 4; i++)
        t[ty + i * 8][tx] = in[(long)(r0 + ty + i * 8) * C + c0 + tx];
    __syncthreads();
#pragma unroll
    for (int i = 0; i < 4; i++)
        out[(long)(c0 + ty + i * 8) * R + r0 + tx] = f2bf(t[tx][ty + i * 8]);
}

// wide 64x64-tile transpose for ff2 (r21, validated).
__global__ __launch_bounds__(256) void transpose_ff2(
    const float* __restrict__ in, ushort_t* __restrict__ out)
{
    __shared__ float t[64][65];
    const int c0 = blockIdx.x << 6;   // input col base, 772 blocks
    const int r0 = blockIdx.y << 6;   // input row base, 8 blocks
    const int tx = threadIdx.x & 63, ty = threadIdx.x >> 6;  // 64 x 4
#pragma unroll
    for (int i = 0; i < 16; i++) {
        int r = ty + i * 4;
        t[r][tx] = in[(long)(r0 + r) * 49408 + c0 + tx];
    }
    __syncthreads();
#pragma unroll
    for (int i = 0; i < 16; i++) {
        int r = ty + i * 4;           // output row within tile = input col
        out[(long)(c0 + r) * 512 + r0 + tx] = f2bf(t[tx][r]);
    }
}

// merged 512x512 transpose x3 (wq,wk,wv -> wqkvT), grid (16,16,3)
__global__ __launch_bounds__(256) void transpose_bf3(
    const float* __restrict__ s0, const float* __restrict__ s1,
    const float* __restrict__ s2, ushort_t* __restrict__ out)
{
    __shared__ float t[32][33];
    const float* in = (blockIdx.z == 0) ? s0 : (blockIdx.z == 1) ? s1 : s2;
    ushort_t* o = out + (long)blockIdx.z * 512 * 512;
    int c0 = blockIdx.x << 5, r0 = blockIdx.y << 5;
    int tx = threadIdx.x, ty = threadIdx.y;
#pragma unroll
    for (int i = 0; i < 4; i++)
        t[ty + i * 8][tx] = in[(long)(r0 + ty + i * 8) * 512 + c0 + tx];
    __syncthreads();
#pragma unroll
    for (int i = 0; i < 4; i++)
        o[(long)(c0 + ty + i * 8) * 512 + r0 + tx] = f2bf(t[tx][ty + i * 8]);
}

// concat 3 x [512] f32 bias vectors
__global__ __launch_bounds__(256) void biascat(
    const float* __restrict__ b0, const float* __restrict__ b1,
    const float* __restrict__ b2, float* __restrict__ out)
{
    int i = blockIdx.x * 256 + threadIdx.x;  // [0,1536)
    const float* s = (i < 512) ? b0 : (i < 1024) ? b1 : b2;
    out[i] = s[i & 511];
}

// f32 [validR][C] -> bf16 [Rpad][C] with zero pad
__global__ __launch_bounds__(256) void conv_pad(
    const float* __restrict__ in, ushort_t* __restrict__ out,
    int validR, int C, int total)
{
    int idx = blockIdx.x * 256 + threadIdx.x;
    if (idx >= total) return;
    int r = idx / C;
    float v = 0.f;
    if (r < validR) v = in[idx];
    out[idx] = f2bf(v);
}

// gather final-LN bf16 rows for txt positions -> Atxt (fallback path only)
__global__ __launch_bounds__(256) void gather_txt(
    const ushort_t* __restrict__ xb, ushort_t* __restrict__ At)
{
    int idx = blockIdx.x * 256 + threadIdx.x;
    if (idx >= 2560 * 512) return;
    int r = idx >> 9, c = idx & 511;
    if (r < 2432) {
        int b = r / 76, t = r - b * 76;
        At[idx] = xb[((long)(b * 126 + 50 + t) << 9) + c];
    } else {
        At[idx] = 0;
    }
}

// build x = LN(concat(img_out, tok_emb[cap]+pos)) ; rows >= 4032 zeroed
__global__ __launch_bounds__(64) void build_x(
    const float* __restrict__ imgout, const int* __restrict__ cap,
    const float* __restrict__ tok, const float* __restrict__ pos,
    const float* __restrict__ g, const float* __restrict__ bb,
    float* __restrict__ x, ushort_t* __restrict__ xb)
{
    int r = blockIdx.x, lane = threadIdx.x;
    int c0 = lane << 3;
    long base = ((long)r << 9) + c0;
    if (r >= 4032) {
        *(f32x4*)(x + base) = (f32x4)0.f;
        *(f32x4*)(x + base + 4) = (f32x4)0.f;
        *(bf8v*)(xb + base) = (bf8v)0;
        return;
    }
    int b = r / 126, s = r - b * 126;
    float v[8];
    if (s < 50) {
        const float* src = imgout + ((long)(b * 50 + s) << 9) + c0;
        f32x4 a0 = *(const f32x4*)src, a1 = *(const f32x4*)(src + 4);
#pragma unroll
        for (int i = 0; i < 4; i++) { v[i] = a0[i]; v[4 + i] = a1[i]; }
    } else {
        int t = s - 50;
        int id = cap[b * 76 + t];
        const float* s1 = tok + ((long)id << 9) + c0;
        const float* s2 = pos + ((long)t << 9) + c0;
        f32x4 a0 = *(const f32x4*)s1, a1 = *(const f32x4*)(s1 + 4);
        f32x4 b0 = *(const f32x4*)s2, b1 = *(const f32x4*)(s2 + 4);
#pragma unroll
        for (int i = 0; i < 4; i++) { v[i] = a0[i] + b0[i]; v[4 + i] = a1[i] + b1[i]; }
    }
    float sum = 0.f, sq = 0.f;
#pragma unroll
    for (int i = 0; i < 8; i++) { sum += v[i]; sq += v[i] * v[i]; }
#pragma unroll
    for (int o = 32; o >= 1; o >>= 1) { sum += __shfl_xor(sum, o); sq += __shfl_xor(sq, o); }
    float mean = sum * (1.f / 512.f);
    float var = sq * (1.f / 512.f) - mean * mean;
    float inv = rsqrtf(var + 1e-5f);
    bf8v ob;
#pragma unroll
    for (int i = 0; i < 8; i++) {
        float y = (v[i] - mean) * inv * g[c0 + i] + bb[c0 + i];
        x[base + i] = y;
        ob[i] = f2bf(y);
    }
    *(bf8v*)(xb + base) = ob;
}

// ---------------------------------------------------------------------------
extern "C" void kernel_launch(void* const* d_in, const int* in_sizes, int n_in,
                              void* d_out, int out_size, void* d_ws, size_t ws_size,
                              hipStream_t stream)
{
    const float* img   = (const float*)d_in[0];   // [32,50,768]
    const int*   cap   = (const int*)  d_in[1];   // [32,76]
    const float* tok   = (const float*)d_in[2];   // [49408,512]
    const float* pos   = (const float*)d_in[3];   // [76,512]
    const float* ff0_w = (const float*)d_in[4];   // [768,512]
    const float* ff0_b = (const float*)d_in[5];
    const float* wq    = (const float*)d_in[6];
    const float* wq_b  = (const float*)d_in[7];
    const float* wk    = (const float*)d_in[8];
    const float* wk_b  = (const float*)d_in[9];
    const float* wv    = (const float*)d_in[10];
    const float* wv_b  = (const float*)d_in[11];
    const float* ln_g  = (const float*)d_in[12];
    const float* ln_b  = (const float*)d_in[13];
    const float* ff1_w = (const float*)d_in[14];
    const float* ff1_b = (const float*)d_in[15];
    const float* ff2_w = (const float*)d_in[16];  // [512,49408]
    const float* ff2_b = (const float*)d_in[17];

    char* ws = (char*)d_ws;
    size_t o = 0;
    auto alloc = [&](size_t bytes) { size_t r = o; o += (bytes + 255) & ~(size_t)255; return r; };

    float*    x     = (float*)   (ws + alloc(4096ull * 512 * 4));
    ushort_t* xb    = (ushort_t*)(ws + alloc(4096ull * 512 * 2));
    float*    tmpf  = (float*)   (ws + alloc(4096ull * 512 * 4));   // img_out
    ushort_t* qkvb  = (ushort_t*)(ws + alloc(4096ull * 1536 * 2));  // [4096][q|k|v]
    ushort_t* Atxt  = (ushort_t*)(ws + alloc(2560ull * 512 * 2));   // fallback only
    ushort_t* Aimg  = (ushort_t*)(ws + alloc(1664ull * 768 * 2));
    ushort_t* wqkvT = (ushort_t*)(ws + alloc(1536ull * 512 * 2));   // [wqT;wkT;wvT]
    ushort_t* ff0T  = (ushort_t*)(ws + alloc(512ull * 768 * 2));
    ushort_t* ff1T  = (ushort_t*)(ws + alloc(512ull * 512 * 2));
    float*    bcat  = (float*)   (ws + alloc(1536 * 4));
    size_t base_bytes = o;
    size_t ff2T_bytes = 49408ull * 512 * 2;                          // 50.6 MB
    bool use_ff2T = (ws_size >= base_bytes + ff2T_bytes + 256);
    ushort_t* ff2T = use_ff2T ? (ushort_t*)(ws + alloc(ff2T_bytes)) : nullptr;

    dim3 b32x8(32, 8);

    transpose_bf3<<<dim3(16, 16, 3), b32x8, 0, stream>>>(wq, wk, wv, wqkvT);
    transpose_bf<<<dim3(16, 24), b32x8, 0, stream>>>(ff0_w, ff0T, 768, 512);
    transpose_bf<<<dim3(16, 16), b32x8, 0, stream>>>(ff1_w, ff1T, 512, 512);
    biascat<<<6, 256, 0, stream>>>(wq_b, wk_b, wv_b, bcat);
    if (use_ff2T)
        transpose_ff2<<<dim3(772, 8), 256, 0, stream>>>(ff2_w, ff2T);
    conv_pad<<<(1664 * 768 + 255) / 256, 256, 0, stream>>>(img, Aimg, 1600, 768, 1664 * 768);

    // ff0: img_out = Aimg @ ff0T^T + ff0_b -> tmpf [1600][512]
    gemm_bf16<0, 0, 0><<<dim3(4, 13, 1), 256, 0, stream>>>(
        Aimg, ff0T, tmpf, nullptr, ff0_b, 768, 768, 768, 512, 0, 0, 0, 1600, 1.f);

    build_x<<<4096, 64, 0, stream>>>(tmpf, cap, tok, pos, ln_g, ln_b, x, xb);

    for (int l = 0; l < 2; l++) {
        // fused qkv: [4096][1536] = xb @ WqkvT^T + bcat   (wv_b included in V)
        gemm_bf16<0, 0, 0><<<dim3(12, 32, 1), 256, 0, stream>>>(
            xb, wqkvT, nullptr, qkvb, bcat, 512, 512, 512, 1536, 0, 0, 0, 4096, 1.f);
        // fused attention + residual-LN: writes x, xb directly
        attn_fused<<<dim3(2, 32), 512, 0, stream>>>(qkvb, x, xb, ln_g, ln_b);
        // fused ff1 + residual-LN: updates x, xb in place
        ff1_fused<<<126, 512, 0, stream>>>(xb, ff1T, ff1_b, x, ln_g, ln_b);
    }

    // logits (f32 out): d_out = gather(xb) @ ff2T^T + ff2_b
    if (use_ff2T) {
        gemm_big<<<dim3(193, 10), 512, 0, stream>>>(
            xb, ff2T, (float*)d_out, ff2_b, 512, 512, 49408, 2432);
    } else {
        gather_txt<<<(2560 * 512 + 255) / 256, 256, 0, stream>>>(xb, Atxt);
        gemm_bf16<1, 1, 0><<<dim3(386, 20, 1), 256, 0, stream>>>(
            Atxt, ff2_w, (float*)d_out, nullptr, ff2_b, 512, 512, 49408, 49408,
            0, 0, 0, 2432, 1.f);
    }
}

// Round 27
// 425.262 us; speedup vs baseline: 1.0286x; 1.0286x over previous
//
#include <hip/hip_runtime.h>

typedef unsigned short ushort_t;
typedef __attribute__((ext_vector_type(8))) short short8;
typedef __attribute__((ext_vector_type(4))) float f32x4;
typedef __attribute__((ext_vector_type(4))) unsigned short bf4;
typedef __attribute__((ext_vector_type(8))) unsigned short bf8v;

__device__ __forceinline__ ushort_t f2bf(float f) {
    union { float f; unsigned u; } v; v.f = f;
    unsigned r = v.u + 0x7FFFu + ((v.u >> 16) & 1u);
    return (ushort_t)(r >> 16);
}

__device__ __forceinline__ void g2lds16(const ushort_t* g, ushort_t* l) {
    __builtin_amdgcn_global_load_lds(
        (const __attribute__((address_space(1))) void*)g,
        (__attribute__((address_space(3))) void*)l, 16, 0, 0);
}

#define LDT 72  // padded LDS row stride (reg-staged paths)

// ---------------------------------------------------------------------------
// gemm_big: logits GEMM (r14 structure + r17 fused text-gather in A-staging).
// r27: + bijective XCD-aware block remap (T1/m204) BEFORE the tN-group
// swizzle: xcd = lin0 % 8 gets a contiguous logical range, so the 8 B-panels
// of a tN-group (2.1 MB, fits 4 MB XCD L2) are re-read L2-locally instead of
// scattering over 8 XCDs' L2s and falling through to L3. nwg=1930 (q=241,
// r=2) -> must use the bijective split form (naive %8 is non-bijective).
// ---------------------------------------------------------------------------
__global__ __launch_bounds__(512) void gemm_big(
    const ushort_t* __restrict__ xb, const ushort_t* __restrict__ B,
    float* __restrict__ C, const float* __restrict__ bias,
    int K, int ldb, int ldc, int validM)
{
    __shared__ __attribute__((aligned(16))) ushort_t As[2][256 * 64];
    __shared__ __attribute__((aligned(16))) ushort_t Bs[2][256 * 64];

    const int tid = threadIdx.x;
    const int lane = tid & 63;
    const int wave = tid >> 6;       // 0..7
    const int wr = wave >> 2;        // 0..1 : 128-row band
    const int wc = wave & 3;         // 0..3 : 64-col slice
    int tN, tM;
    {
        const int lin0 = blockIdx.x + blockIdx.y * gridDim.x;
        const int nwg = gridDim.x * gridDim.y;
        // bijective XCD remap (m204): XCD (= lin0 & 7 dispatch round-robin)
        // owns a contiguous logical range.
        const int q = nwg >> 3, r = nwg & 7;
        const int xcd = lin0 & 7;
        const int lin = (xcd < r ? xcd * (q + 1)
                                 : r * (q + 1) + (xcd - r) * q) + (lin0 >> 3);
        const int TM = gridDim.y;
        const int full = gridDim.x >> 3;
        const int per = TM << 3;
        const int g = lin / per;
        if (g < full) {
            const int rem = lin - g * per;
            tM = rem >> 3;
            tN = (g << 3) + (rem & 7);
        } else {
            const int rem = lin - full * per;
            const int w = gridDim.x - (full << 3);
            tM = rem / w;
            tN = (full << 3) + rem - tM * w;
        }
    }
    const int n0 = tN * 256;
    const ushort_t* Bbase = B + (long)n0 * ldb;

    f32x4 acc[8][4];
#pragma unroll
    for (int m = 0; m < 8; m++)
#pragma unroll
        for (int n = 0; n < 4; n++) acc[m][n] = (f32x4)0.f;

    auto STAGE = [&](int buf, int ks) {
#pragma unroll
        for (int i = 0; i < 4; i++) {
            int ch = i * 512 + tid;
            int row = ch >> 3, c16 = ch & 7;
            int c16s = c16 ^ (row & 7);
            int gr = tM * 256 + row;
            if (gr > 2431) gr = 2431;            // masked by validM at store
            int bb = gr / 76;
            int xrow = bb * 126 + 50 + (gr - bb * 76);
            g2lds16(xb + (long)xrow * 512 + ks + (c16s << 3),
                    &As[buf][(i * 512 + wave * 64) * 8]);
        }
#pragma unroll
        for (int i = 0; i < 4; i++) {
            int ch = i * 512 + tid;
            int row = ch >> 3, c16 = ch & 7;
            int c16s = c16 ^ (row & 7);
            g2lds16(Bbase + (long)row * ldb + ks + (c16s << 3),
                    &Bs[buf][(i * 512 + wave * 64) * 8]);
        }
    };

    const int nt = K >> 6;
    STAGE(0, 0);
    for (int t = 0; t < nt; ++t) {
        if (t + 1 < nt) {
            STAGE((t + 1) & 1, (t + 1) << 6);
            asm volatile("s_waitcnt vmcnt(8)" ::: "memory");   // tile t done
        } else {
            asm volatile("s_waitcnt vmcnt(0)" ::: "memory");
        }
        asm volatile("s_barrier" ::: "memory");

        const ushort_t* Ac = As[t & 1];
        const ushort_t* Bc = Bs[t & 1];
        __builtin_amdgcn_s_setprio(1);
#pragma unroll
        for (int ksub = 0; ksub < 2; ksub++) {
            const int kk = ksub * 32 + ((lane >> 4) << 3);
            const int kc = kk >> 3;
            short8 af[8], bfr[4];
#pragma unroll
            for (int m = 0; m < 8; m++) {
                const int r = (wr << 7) + m * 16 + (lane & 15);
                af[m] = *(const short8*)(Ac + r * 64 + ((kc ^ (r & 7)) << 3));
            }
#pragma unroll
            for (int n = 0; n < 4; n++) {
                const int r = (wc << 6) + n * 16 + (lane & 15);
                bfr[n] = *(const short8*)(Bc + r * 64 + ((kc ^ (r & 7)) << 3));
            }
#pragma unroll
            for (int m = 0; m < 8; m++)
#pragma unroll
                for (int n = 0; n < 4; n++)
                    acc[m][n] = __builtin_amdgcn_mfma_f32_16x16x32_bf16(
                        af[m], bfr[n], acc[m][n], 0, 0, 0);
        }
        __builtin_amdgcn_s_setprio(0);
        asm volatile("s_barrier" ::: "memory");
    }

    const int rb = (wr << 7) + ((lane >> 4) << 2);
    const int cb = (wc << 6) + (lane & 15);
#pragma unroll
    for (int m = 0; m < 8; m++) {
#pragma unroll
        for (int i = 0; i < 4; i++) {
            int r = tM * 256 + rb + m * 16 + i;
            if (r >= validM) continue;
#pragma unroll
            for (int n = 0; n < 4; n++) {
                int cg = n0 + cb + n * 16;
                C[(long)r * ldc + cg] = acc[m][n][i] + bias[cg];
            }
        }
    }
}

// ---------------------------------------------------------------------------
// ff1_fused: y = LN(x + xb@ff1T^T + ff1_b) in place (r20, validated).
// ---------------------------------------------------------------------------
__global__ __launch_bounds__(512) void ff1_fused(
    ushort_t* __restrict__ xbg, const ushort_t* __restrict__ ff1T,
    const float* __restrict__ bias, float* __restrict__ xg,
    const float* __restrict__ ln_g, const float* __restrict__ ln_b)
{
    __shared__ __attribute__((aligned(16))) ushort_t As[32 * 64];    // 4 KB
    __shared__ __attribute__((aligned(16))) ushort_t Bs[512 * 64];   // 64 KB
    __shared__ float redm[4 * 32];
    __shared__ float reds[4 * 32];

    const int tid = threadIdx.x;
    const int lane = tid & 63;
    const int wave = tid >> 6;
    const int wr = wave >> 2;     // 0..1 : 16-row band
    const int wc = wave & 3;      // 0..3 : 128-col slice
    const int r0 = blockIdx.x << 5;   // 32 rows/block, 126 blocks, all valid

    f32x4 acc[8];
#pragma unroll
    for (int n = 0; n < 8; n++) acc[n] = (f32x4)0.f;

    auto STAGE = [&](int ks) {
        // chunk space: A = 256 chunks (32x64), B = 4096 chunks (512x64)
#pragma unroll
        for (int i = 0; i < 9; i++) {
            int cb = i * 512 + wave * 64;       // wave-uniform chunk base
            if (cb >= 4352) continue;
            int ch = cb + lane;
            if (cb < 256) {                     // A chunk
                int row = ch >> 3, c16 = ch & 7;
                int c16s = c16 ^ (row & 7);
                g2lds16(xbg + (long)(r0 + row) * 512 + ks + (c16s << 3),
                        &As[cb * 8]);
            } else {                            // B chunk
                int bch = ch - 256;
                int row = bch >> 3, c16 = bch & 7;
                int c16s = c16 ^ (row & 7);
                g2lds16(ff1T + (long)row * 512 + ks + (c16s << 3),
                        &Bs[(cb - 256) * 8]);
            }
        }
    };

    for (int ks = 0; ks < 512; ks += 64) {
        if (ks) asm volatile("s_barrier" ::: "memory");  // prev readers done
        STAGE(ks);
        asm volatile("s_waitcnt vmcnt(0)" ::: "memory");
        asm volatile("s_barrier" ::: "memory");

        __builtin_amdgcn_s_setprio(1);
#pragma unroll
        for (int ksub = 0; ksub < 2; ksub++) {
            const int kc = ksub * 4 + (lane >> 4);
            short8 af;
            {
                const int r = (wr << 4) + (lane & 15);
                af = *(const short8*)(As + r * 64 + ((kc ^ (r & 7)) << 3));
            }
            short8 bfr[8];
#pragma unroll
            for (int n = 0; n < 8; n++) {
                const int r = (wc << 7) + n * 16 + (lane & 15);
                bfr[n] = *(const short8*)(Bs + r * 64 + ((kc ^ (r & 7)) << 3));
            }
#pragma unroll
            for (int n = 0; n < 8; n++)
                acc[n] = __builtin_amdgcn_mfma_f32_16x16x32_bf16(
                    af, bfr[n], acc[n], 0, 0, 0);
        }
        __builtin_amdgcn_s_setprio(0);
    }

    // ---- epilogue: bias + residual + LayerNorm ----
    float gg[8], bb2[8], bi[8];
#pragma unroll
    for (int n = 0; n < 8; n++) {
        int d = (wc << 7) + n * 16 + (lane & 15);
        gg[n] = ln_g[d];
        bb2[n] = ln_b[d];
        bi[n] = bias[d];
    }
    float vv[4][8];
#pragma unroll
    for (int i = 0; i < 4; i++) {
        const int rl = (wr << 4) + ((lane >> 4) << 2) + i;
        const long xrow = (long)(r0 + rl) << 9;
        float s = 0.f, sq = 0.f;
#pragma unroll
        for (int n = 0; n < 8; n++) {
            int d = (wc << 7) + n * 16 + (lane & 15);
            float v = acc[n][i] + bi[n] + xg[xrow + d];
            vv[i][n] = v;
            s += v; sq += v * v;
        }
#pragma unroll
        for (int o = 8; o >= 1; o >>= 1) { s += __shfl_xor(s, o); sq += __shfl_xor(sq, o); }
        if ((lane & 15) == 0) {
            redm[wc * 32 + rl] = s;
            reds[wc * 32 + rl] = sq;
        }
    }
    __syncthreads();
#pragma unroll
    for (int i = 0; i < 4; i++) {
        const int rl = (wr << 4) + ((lane >> 4) << 2) + i;
        float S = redm[rl] + redm[32 + rl] + redm[64 + rl] + redm[96 + rl];
        float SQ = reds[rl] + reds[32 + rl] + reds[64 + rl] + reds[96 + rl];
        float mean = S * (1.f / 512.f);
        float var = SQ * (1.f / 512.f) - mean * mean;
        float inv = rsqrtf(var + 1e-5f);
        const long xrow = (long)(r0 + rl) << 9;
#pragma unroll
        for (int n = 0; n < 8; n++) {
            int d = (wc << 7) + n * 16 + (lane & 15);
            float y = (vv[i][n] - mean) * inv * gg[n] + bb2[n];
            xg[xrow + d] = y;
            xbg[xrow + d] = f2bf(y);
        }
    }
}

// ---------------------------------------------------------------------------
// attn_fused: QK^T + softmax + PV + residual-LN (r18, validated).
// ---------------------------------------------------------------------------
__global__ __launch_bounds__(512) void attn_fused(
    const ushort_t* __restrict__ qkv, float* __restrict__ xg,
    ushort_t* __restrict__ xbg, const float* __restrict__ ln_g,
    const float* __restrict__ ln_b)
{
    __shared__ __attribute__((aligned(16))) ushort_t smem[41984];
    ushort_t* Vs = smem;                      // [512][64]   (phase 3)
    ushort_t* Ps = smem + 32768;              // [64][128]
    float* redm = (float*)(smem + 40960);     // [4][64]
    float* reds = redm + 256;                 // [4][64]
    ushort_t* Qs = smem;                      // [2][64*64]  (phase 1)
    ushort_t* Ks = smem + 8192;               // [2][128*64]

    const int tid = threadIdx.x;
    const int lane = tid & 63;
    const int wave = tid >> 6;
    const int wr = wave >> 2;     // 0..1
    const int wc = wave & 3;      // 0..3
    const int qh = blockIdx.x;    // 0..1
    const int b  = blockIdx.y;    // 0..31
    const long qbase = ((long)(b * 126) + qh * 64) * 1536;
    const long kbase = (long)(b * 126) * 1536 + 512;
    const long vbase = (long)(b * 126) * 1536 + 1024;
    const float rsqd = 0.044194173824159216f;

    // ================= phase 1: S = Q K^T =================
    f32x4 acc[2][2];
#pragma unroll
    for (int m = 0; m < 2; m++)
#pragma unroll
        for (int n = 0; n < 2; n++) acc[m][n] = (f32x4)0.f;

    auto SQK = [&](int buf, int ks) {
        {   // Q tile 64x64: 512 chunks, 1/thread
            int ch = tid;
            int row = ch >> 3, c16 = ch & 7;
            int c16s = c16 ^ (row & 7);
            g2lds16(qkv + qbase + (long)row * 1536 + ks + (c16s << 3),
                    Qs + buf * 4096 + (wave * 64) * 8);
        }
#pragma unroll
        for (int i = 0; i < 2; i++) {  // K tile 128x64: 1024 chunks
            int ch = i * 512 + tid;
            int row = ch >> 3, c16 = ch & 7;
            int c16s = c16 ^ (row & 7);
            g2lds16(qkv + kbase + (long)row * 1536 + ks + (c16s << 3),
                    Ks + buf * 8192 + (i * 512 + wave * 64) * 8);
        }
    };

    SQK(0, 0);
    for (int t = 0; t < 8; ++t) {
        if (t < 7) {
            SQK((t + 1) & 1, (t + 1) << 6);
            asm volatile("s_waitcnt vmcnt(3)" ::: "memory");
        } else {
            asm volatile("s_waitcnt vmcnt(0)" ::: "memory");
        }
        asm volatile("s_barrier" ::: "memory");
        const ushort_t* Qc = Qs + (t & 1) * 4096;
        const ushort_t* Kc = Ks + (t & 1) * 8192;
#pragma unroll
        for (int ksub = 0; ksub < 2; ksub++) {
            const int kc = ksub * 4 + (lane >> 4);
            short8 af[2], bfr[2];
#pragma unroll
            for (int m = 0; m < 2; m++) {
                const int r = (wr << 5) + m * 16 + (lane & 15);
                af[m] = *(const short8*)(Qc + r * 64 + ((kc ^ (r & 7)) << 3));
            }
#pragma unroll
            for (int n = 0; n < 2; n++) {
                const int r = (wc << 5) + n * 16 + (lane & 15);
                bfr[n] = *(const short8*)(Kc + r * 64 + ((kc ^ (r & 7)) << 3));
            }
#pragma unroll
            for (int m = 0; m < 2; m++)
#pragma unroll
                for (int n = 0; n < 2; n++)
                    acc[m][n] = __builtin_amdgcn_mfma_f32_16x16x32_bf16(
                        af[m], bfr[n], acc[m][n], 0, 0, 0);
        }
        asm volatile("s_barrier" ::: "memory");
    }

    // ================= phase 2: masked softmax =================
    float rm[2][4];
#pragma unroll
    for (int m = 0; m < 2; m++) {
#pragma unroll
        for (int i = 0; i < 4; i++) {
            const int rl = (wr << 5) + m * 16 + ((lane >> 4) << 2) + i;
            const int q = qh * 64 + rl;
            float mx = -3.0e38f;
#pragma unroll
            for (int n = 0; n < 2; n++) {
                int j = (wc << 5) + n * 16 + (lane & 15);
                bool ok = (j < 126) && ((j < 50) || (j <= q));
                float s = acc[m][n][i] * rsqd;
                acc[m][n][i] = ok ? s : -3.0e38f;
                if (ok) mx = fmaxf(mx, s);
            }
#pragma unroll
            for (int o = 8; o >= 1; o >>= 1) mx = fmaxf(mx, __shfl_xor(mx, o));
            rm[m][i] = mx;
        }
    }
    if ((lane & 15) == 0) {
#pragma unroll
        for (int m = 0; m < 2; m++)
#pragma unroll
            for (int i = 0; i < 4; i++) {
                int rl = (wr << 5) + m * 16 + ((lane >> 4) << 2) + i;
                redm[wc * 64 + rl] = rm[m][i];
            }
    }
    __syncthreads();
    float rs[2][4];
#pragma unroll
    for (int m = 0; m < 2; m++) {
#pragma unroll
        for (int i = 0; i < 4; i++) {
            const int rl = (wr << 5) + m * 16 + ((lane >> 4) << 2) + i;
            float M = fmaxf(fmaxf(redm[rl], redm[64 + rl]),
                            fmaxf(redm[128 + rl], redm[192 + rl]));
            float sum = 0.f;
#pragma unroll
            for (int n = 0; n < 2; n++) {
                float s = acc[m][n][i];
                float e = (s > -1.0e37f) ? expf(s - M) : 0.f;
                acc[m][n][i] = e;
                sum += e;
            }
#pragma unroll
            for (int o = 8; o >= 1; o >>= 1) sum += __shfl_xor(sum, o);
            rs[m][i] = sum;
        }
    }
    if ((lane & 15) == 0) {
#pragma unroll
        for (int m = 0; m < 2; m++)
#pragma unroll
            for (int i = 0; i < 4; i++) {
                int rl = (wr << 5) + m * 16 + ((lane >> 4) << 2) + i;
                reds[wc * 64 + rl] = rs[m][i];
            }
    }
    __syncthreads();
#pragma unroll
    for (int m = 0; m < 2; m++) {
#pragma unroll
        for (int i = 0; i < 4; i++) {
            const int rl = (wr << 5) + m * 16 + ((lane >> 4) << 2) + i;
            float S = reds[rl] + reds[64 + rl] + reds[128 + rl] + reds[192 + rl];
            float inv = 1.f / S;
#pragma unroll
            for (int n = 0; n < 2; n++) {
                int j = (wc << 5) + n * 16 + (lane & 15);
                int c = j >> 3;
                Ps[rl * 128 + ((c ^ (rl & 7)) << 3) + (j & 7)] =
                    f2bf(acc[m][n][i] * inv);
            }
        }
    }
    __syncthreads();

    // ================= phase 3: attn = P V =================
    f32x4 po[2][8];
#pragma unroll
    for (int m = 0; m < 2; m++)
#pragma unroll
        for (int n = 0; n < 8; n++) po[m][n] = (f32x4)0.f;

    for (int jc = 0; jc < 2; jc++) {
#pragma unroll
        for (int q8 = 0; q8 < 16; q8++) {
            int qid = q8 * 512 + tid;           // 0..8191
            int d = qid & 511, jq = qid >> 9;   // jq 0..15
            const ushort_t* vp = qkv + vbase + (long)(jc * 64 + jq * 4) * 1536 + d;
            bf4 p;
            p[0] = vp[0];
            p[1] = vp[1536];
            p[2] = vp[3072];
            p[3] = vp[4608];
            *(bf4*)(Vs + d * 64 + (((jq >> 1) ^ (d & 7)) << 3) + ((jq & 1) << 2)) = p;
        }
        __syncthreads();
#pragma unroll
        for (int ksub = 0; ksub < 2; ksub++) {
            const int kc = ksub * 4 + (lane >> 4);
            short8 af[2], bv[8];
#pragma unroll
            for (int m = 0; m < 2; m++) {
                const int r = (wr << 5) + m * 16 + (lane & 15);
                const int c = jc * 8 + kc;
                af[m] = *(const short8*)(Ps + r * 128 + ((c ^ (r & 7)) << 3));
            }
#pragma unroll
            for (int n = 0; n < 8; n++) {
                const int r = (wc << 7) + n * 16 + (lane & 15);
                bv[n] = *(const short8*)(Vs + r * 64 + ((kc ^ (r & 7)) << 3));
            }
#pragma unroll
            for (int m = 0; m < 2; m++)
#pragma unroll
                for (int n = 0; n < 8; n++)
                    po[m][n] = __builtin_amdgcn_mfma_f32_16x16x32_bf16(
                        af[m], bv[n], po[m][n], 0, 0, 0);
        }
        __syncthreads();
    }

    // ========= phase 4: residual + LayerNorm -> x, xb =========
    float gg[8], bb2[8];
#pragma unroll
    for (int n = 0; n < 8; n++) {
        int d = (wc << 7) + n * 16 + (lane & 15);
        gg[n] = ln_g[d];
        bb2[n] = ln_b[d];
    }
#pragma unroll
    for (int m = 0; m < 2; m++) {
#pragma unroll
        for (int i = 0; i < 4; i++) {
            const int rl = (wr << 5) + m * 16 + ((lane >> 4) << 2) + i;
            const int q = qh * 64 + rl;
            const long xrow = ((long)(b * 126 + q)) << 9;   // q>=126: pad row, zeroed
            float s = 0.f, sq = 0.f;
#pragma unroll
            for (int n = 0; n < 8; n++) {
                int d = (wc << 7) + n * 16 + (lane & 15);
                float v = po[m][n][i] + xg[xrow + d];
                po[m][n][i] = v;
                s += v; sq += v * v;
            }
#pragma unroll
            for (int o = 8; o >= 1; o >>= 1) { s += __shfl_xor(s, o); sq += __shfl_xor(sq, o); }
            if ((lane & 15) == 0) {
                redm[wc * 64 + rl] = s;
                reds[wc * 64 + rl] = sq;
            }
        }
    }
    __syncthreads();
#pragma unroll
    for (int m = 0; m < 2; m++) {
#pragma unroll
        for (int i = 0; i < 4; i++) {
            const int rl = (wr << 5) + m * 16 + ((lane >> 4) << 2) + i;
            const int q = qh * 64 + rl;
            if (q >= 126) continue;
            float S = redm[rl] + redm[64 + rl] + redm[128 + rl] + redm[192 + rl];
            float SQ = reds[rl] + reds[64 + rl] + reds[128 + rl] + reds[192 + rl];
            float mean = S * (1.f / 512.f);
            float var = SQ * (1.f / 512.f) - mean * mean;
            float inv = rsqrtf(var + 1e-5f);
            const long xrow = ((long)(b * 126 + q)) << 9;
#pragma unroll
            for (int n = 0; n < 8; n++) {
                int d = (wc << 7) + n * 16 + (lane & 15);
                float y = (po[m][n][i] - mean) * inv * gg[n] + bb2[n];
                xg[xrow + d] = y;
                xbg[xrow + d] = f2bf(y);
            }
        }
    }
}

// ---------------------------------------------------------------------------
// Batched bf16 GEMM (128x128): BSRC=0 dbuf + counted vmcnt; BSRC=1 reg-staged
// fallback (validated).
// ---------------------------------------------------------------------------
template <int BSRC, int SWZ, int NT>
__global__ __launch_bounds__(256) void gemm_bf16(
    const ushort_t* __restrict__ A, const void* __restrict__ Bv,
    float* __restrict__ C, ushort_t* __restrict__ Cb,
    const float* __restrict__ bias,
    int K, int lda, int ldb, int ldc,
    long sA, long sB, long sC,
    int validM, float scale)
{
    constexpr int LS = (BSRC == 0) ? 64 : LDT;
    constexpr int NBUF = (BSRC == 0) ? 2 : 1;
    __shared__ __attribute__((aligned(16))) ushort_t As[NBUF * 128 * LS];
    __shared__ __attribute__((aligned(16))) ushort_t Bs[NBUF * 128 * LS];

    const int tid = threadIdx.x;
    const int lane = tid & 63;
    const int wave = tid >> 6;
    const int wr = wave >> 1, wc = wave & 1;
    int tN = blockIdx.x, tM = blockIdx.y;
    const int bz = blockIdx.z;
    if (SWZ) {
        const int lin = blockIdx.x + blockIdx.y * gridDim.x;
        const int TM = gridDim.y;
        const int full = gridDim.x >> 3;
        const int per = TM << 3;
        const int g = lin / per;
        if (g < full) {
            const int rem = lin - g * per;
            tM = rem >> 3;
            tN = (g << 3) + (rem & 7);
        } else {
            const int rem = lin - full * per;
            const int w = gridDim.x - (full << 3);
            tM = rem / w;
            tN = (full << 3) + rem - tM * w;
        }
    }
    const int n0 = tN * 128;

    const ushort_t* Abase = A + (long)bz * sA + (long)tM * 128 * lda;
    const ushort_t* Bb = (BSRC == 0)
        ? (const ushort_t*)Bv + (long)bz * sB + (long)n0 * ldb : nullptr;
    const float* Bf = (BSRC == 1)
        ? (const float*)Bv + (long)bz * sB : nullptr;

    f32x4 acc[4][4];
#pragma unroll
    for (int m = 0; m < 4; m++)
#pragma unroll
        for (int n = 0; n < 4; n++) acc[m][n] = (f32x4)0.f;

    if (BSRC == 0) {
        auto STAGE = [&](int buf, int ks) {
            ushort_t* Ad = As + buf * (128 * 64);
            ushort_t* Bd = Bs + buf * (128 * 64);
#pragma unroll
            for (int i = 0; i < 4; i++) {
                int ch = wave * 256 + i * 64 + lane;
                int row = ch >> 3, c16 = ch & 7;
                int c16s = c16 ^ (row & 7);
                g2lds16(Abase + (long)row * lda + ks + (c16s << 3),
                        Ad + (wave * 256 + i * 64) * 8);
            }
#pragma unroll
            for (int i = 0; i < 4; i++) {
                int ch = wave * 256 + i * 64 + lane;
                int row = ch >> 3, c16 = ch & 7;
                int c16s = c16 ^ (row & 7);
                g2lds16(Bb + (long)row * ldb + ks + (c16s << 3),
                        Bd + (wave * 256 + i * 64) * 8);
            }
        };

        const int nt = K >> 6;
        STAGE(0, 0);
        for (int t = 0; t < nt; ++t) {
            if (t + 1 < nt) {
                STAGE((t + 1) & 1, (t + 1) << 6);
                asm volatile("s_waitcnt vmcnt(8)" ::: "memory");
            } else {
                asm volatile("s_waitcnt vmcnt(0)" ::: "memory");
            }
            asm volatile("s_barrier" ::: "memory");

            const ushort_t* Ac = As + (t & 1) * (128 * 64);
            const ushort_t* Bc = Bs + (t & 1) * (128 * 64);
#pragma unroll
            for (int ksub = 0; ksub < 2; ksub++) {
                const int kk = ksub * 32 + ((lane >> 4) << 3);
                const int kc = kk >> 3;
                short8 af[4], bfr[4];
#pragma unroll
                for (int m = 0; m < 4; m++) {
                    const int r = (wr << 6) + m * 16 + (lane & 15);
                    af[m] = *(const short8*)(Ac + r * 64 + ((kc ^ (r & 7)) << 3));
                }
#pragma unroll
                for (int n = 0; n < 4; n++) {
                    const int r = (wc << 6) + n * 16 + (lane & 15);
                    bfr[n] = *(const short8*)(Bc + r * 64 + ((kc ^ (r & 7)) << 3));
                }
#pragma unroll
                for (int m = 0; m < 4; m++)
#pragma unroll
                    for (int n = 0; n < 4; n++)
                        acc[m][n] = __builtin_amdgcn_mfma_f32_16x16x32_bf16(
                            af[m], bfr[n], acc[m][n], 0, 0, 0);
            }
            asm volatile("s_barrier" ::: "memory");
        }
    } else {
        for (int ks = 0; ks < K; ks += 64) {
            short8 ar[4];
#pragma unroll
            for (int i = 0; i < 4; i++) {
                int ch = wave * 256 + i * 64 + lane;
                int row = ch >> 3, c16 = ch & 7;
                ar[i] = *(const short8*)(Abase + (long)row * lda + ks + (c16 << 3));
            }
            bf4 pk[8];
#pragma unroll
            for (int q = 0; q < 8; q++) {
                int qid = q * 256 + tid;
                int n = qid & 127, kq = qid >> 7;
                const float* wp = Bf + (long)(ks + kq * 4) * ldb + n0 + n;
                bf4 p;
                p[0] = f2bf(wp[0]);
                p[1] = f2bf(wp[ldb]);
                p[2] = f2bf(wp[2 * (long)ldb]);
                p[3] = f2bf(wp[3 * (long)ldb]);
                pk[q] = p;
            }
            if (ks) __syncthreads();
#pragma unroll
            for (int i = 0; i < 4; i++) {
                int ch = wave * 256 + i * 64 + lane;
                int row = ch >> 3, c16 = ch & 7;
                *(short8*)(As + row * LS + (c16 << 3)) = ar[i];
            }
#pragma unroll
            for (int q = 0; q < 8; q++) {
                int qid = q * 256 + tid;
                int n = qid & 127, kq = qid >> 7;
                *(bf4*)(Bs + n * LS + (kq << 2)) = pk[q];
            }
            __syncthreads();

#pragma unroll
            for (int ksub = 0; ksub < 2; ksub++) {
                const int kk = ksub * 32 + ((lane >> 4) << 3);
                short8 af[4], bfr[4];
#pragma unroll
                for (int m = 0; m < 4; m++) {
                    const int r = (wr << 6) + m * 16 + (lane & 15);
                    af[m] = *(const short8*)(As + r * LS + kk);
                }
#pragma unroll
                for (int n = 0; n < 4; n++) {
                    const int r = (wc << 6) + n * 16 + (lane & 15);
                    bfr[n] = *(const short8*)(Bs + r * LS + kk);
                }
#pragma unroll
                for (int m = 0; m < 4; m++)
#pragma unroll
                    for (int n = 0; n < 4; n++)
                        acc[m][n] = __builtin_amdgcn_mfma_f32_16x16x32_bf16(
                            af[m], bfr[n], acc[m][n], 0, 0, 0);
            }
            if (ks + 64 < K) __syncthreads();
        }
    }

    const int rb = (wr << 6) + ((lane >> 4) << 2);
    const int cb = (wc << 6) + (lane & 15);
#pragma unroll
    for (int m = 0; m < 4; m++) {
#pragma unroll
        for (int i = 0; i < 4; i++) {
            int r = tM * 128 + rb + m * 16 + i;
            if (r >= validM) continue;
#pragma unroll
            for (int n = 0; n < 4; n++) {
                int cg = n0 + cb + n * 16;
                float v = acc[m][n][i] * scale + (bias ? bias[cg] : 0.f);
                long off = (long)bz * sC + (long)r * ldc + cg;
                if (C) {
                    if (NT) __builtin_nontemporal_store(v, &C[off]);
                    else    C[off] = v;
                }
                if (Cb) Cb[off] = f2bf(v);
            }
        }
    }
}

// ---------------------------------------------------------------------------
// transpose f32 [R][C] -> bf16 [C][R]   (small weights)
// ---------------------------------------------------------------------------
__global__ __launch_bounds__(256) void transpose_bf(
    const float* __restrict__ in, ushort_t* __restrict__ out, int R, int C)
{
    __shared__ float t[32][33];
    int c0 = blockIdx.x << 5, r0 = blockIdx.y << 5;
    int tx = threadIdx.x, ty = threadIdx.y;
#pragma unroll
    for (int i = 0; i < 4; i++)
        t[ty + i * 8][tx] = in[(long)(r0 + ty + i * 8) * C + c0 + tx];
    __syncthreads();
#pragma unroll
    for (int i = 0; i < 4; i++)
        out[(long)(c0 + ty + i * 8) * R + r0 + tx] = f2bf(t[tx][ty + i * 8]);
}

// wide 64x64-tile transpose for ff2 (r21, validated).
__global__ __launch_bounds__(256) void transpose_ff2(
    const float* __restrict__ in, ushort_t* __restrict__ out)
{
    __shared__ float t[64][65];
    const int c0 = blockIdx.x << 6;   // input col base, 772 blocks
    const int r0 = blockIdx.y << 6;   // input row base, 8 blocks
    const int tx = threadIdx.x & 63, ty = threadIdx.x >> 6;  // 64 x 4
#pragma unroll
    for (int i = 0; i < 16; i++) {
        int r = ty + i * 4;
        t[r][tx] = in[(long)(r0 + r) * 49408 + c0 + tx];
    }
    __syncthreads();
#pragma unroll
    for (int i = 0; i < 16; i++) {
        int r = ty + i * 4;           // output row within tile = input col
        out[(long)(c0 + r) * 512 + r0 + tx] = f2bf(t[tx][r]);
    }
}

// merged 512x512 transpose x3 (wq,wk,wv -> wqkvT), grid (16,16,3)
__global__ __launch_bounds__(256) void transpose_bf3(
    const float* __restrict__ s0, const float* __restrict__ s1,
    const float* __restrict__ s2, ushort_t* __restrict__ out)
{
    __shared__ float t[32][33];
    const float* in = (blockIdx.z == 0) ? s0 : (blockIdx.z == 1) ? s1 : s2;
    ushort_t* o = out + (long)blockIdx.z * 512 * 512;
    int c0 = blockIdx.x << 5, r0 = blockIdx.y << 5;
    int tx = threadIdx.x, ty = threadIdx.y;
#pragma unroll
    for (int i = 0; i < 4; i++)
        t[ty + i * 8][tx] = in[(long)(r0 + ty + i * 8) * 512 + c0 + tx];
    __syncthreads();
#pragma unroll
    for (int i = 0; i < 4; i++)
        o[(long)(c0 + ty + i * 8) * 512 + r0 + tx] = f2bf(t[tx][ty + i * 8]);
}

// concat 3 x [512] f32 bias vectors
__global__ __launch_bounds__(256) void biascat(
    const float* __restrict__ b0, const float* __restrict__ b1,
    const float* __restrict__ b2, float* __restrict__ out)
{
    int i = blockIdx.x * 256 + threadIdx.x;  // [0,1536)
    const float* s = (i < 512) ? b0 : (i < 1024) ? b1 : b2;
    out[i] = s[i & 511];
}

// f32 [validR][C] -> bf16 [Rpad][C] with zero pad
__global__ __launch_bounds__(256) void conv_pad(
    const float* __restrict__ in, ushort_t* __restrict__ out,
    int validR, int C, int total)
{
    int idx = blockIdx.x * 256 + threadIdx.x;
    if (idx >= total) return;
    int r = idx / C;
    float v = 0.f;
    if (r < validR) v = in[idx];
    out[idx] = f2bf(v);
}

// gather final-LN bf16 rows for txt positions -> Atxt (fallback path only)
__global__ __launch_bounds__(256) void gather_txt(
    const ushort_t* __restrict__ xb, ushort_t* __restrict__ At)
{
    int idx = blockIdx.x * 256 + threadIdx.x;
    if (idx >= 2560 * 512) return;
    int r = idx >> 9, c = idx & 511;
    if (r < 2432) {
        int b = r / 76, t = r - b * 76;
        At[idx] = xb[((long)(b * 126 + 50 + t) << 9) + c];
    } else {
        At[idx] = 0;
    }
}

// build x = LN(concat(img_out, tok_emb[cap]+pos)) ; rows >= 4032 zeroed
__global__ __launch_bounds__(64) void build_x(
    const float* __restrict__ imgout, const int* __restrict__ cap,
    const float* __restrict__ tok, const float* __restrict__ pos,
    const float* __restrict__ g, const float* __restrict__ bb,
    float* __restrict__ x, ushort_t* __restrict__ xb)
{
    int r = blockIdx.x, lane = threadIdx.x;
    int c0 = lane << 3;
    long base = ((long)r << 9) + c0;
    if (r >= 4032) {
        *(f32x4*)(x + base) = (f32x4)0.f;
        *(f32x4*)(x + base + 4) = (f32x4)0.f;
        *(bf8v*)(xb + base) = (bf8v)0;
        return;
    }
    int b = r / 126, s = r - b * 126;
    float v[8];
    if (s < 50) {
        const float* src = imgout + ((long)(b * 50 + s) << 9) + c0;
        f32x4 a0 = *(const f32x4*)src, a1 = *(const f32x4*)(src + 4);
#pragma unroll
        for (int i = 0; i < 4; i++) { v[i] = a0[i]; v[4 + i] = a1[i]; }
    } else {
        int t = s - 50;
        int id = cap[b * 76 + t];
        const float* s1 = tok + ((long)id << 9) + c0;
        const float* s2 = pos + ((long)t << 9) + c0;
        f32x4 a0 = *(const f32x4*)s1, a1 = *(const f32x4*)(s1 + 4);
        f32x4 b0 = *(const f32x4*)s2, b1 = *(const f32x4*)(s2 + 4);
#pragma unroll
        for (int i = 0; i < 4; i++) { v[i] = a0[i] + b0[i]; v[4 + i] = a1[i] + b1[i]; }
    }
    float sum = 0.f, sq = 0.f;
#pragma unroll
    for (int i = 0; i < 8; i++) { sum += v[i]; sq += v[i] * v[i]; }
#pragma unroll
    for (int o = 32; o >= 1; o >>= 1) { sum += __shfl_xor(sum, o); sq += __shfl_xor(sq, o); }
    float mean = sum * (1.f / 512.f);
    float var = sq * (1.f / 512.f) - mean * mean;
    float inv = rsqrtf(var + 1e-5f);
    bf8v ob;
#pragma unroll
    for (int i = 0; i < 8; i++) {
        float y = (v[i] - mean) * inv * g[c0 + i] + bb[c0 + i];
        x[base + i] = y;
        ob[i] = f2bf(y);
    }
    *(bf8v*)(xb + base) = ob;
}

// ---------------------------------------------------------------------------
extern "C" void kernel_launch(void* const* d_in, const int* in_sizes, int n_in,
                              void* d_out, int out_size, void* d_ws, size_t ws_size,
                              hipStream_t stream)
{
    const float* img   = (const float*)d_in[0];   // [32,50,768]
    const int*   cap   = (const int*)  d_in[1];   // [32,76]
    const float* tok   = (const float*)d_in[2];   // [49408,512]
    const float* pos   = (const float*)d_in[3];   // [76,512]
    const float* ff0_w = (const float*)d_in[4];   // [768,512]
    const float* ff0_b = (const float*)d_in[5];
    const float* wq    = (const float*)d_in[6];
    const float* wq_b  = (const float*)d_in[7];
    const float* wk    = (const float*)d_in[8];
    const float* wk_b  = (const float*)d_in[9];
    const float* wv    = (const float*)d_in[10];
    const float* wv_b  = (const float*)d_in[11];
    const float* ln_g  = (const float*)d_in[12];
    const float* ln_b  = (const float*)d_in[13];
    const float* ff1_w = (const float*)d_in[14];
    const float* ff1_b = (const float*)d_in[15];
    const float* ff2_w = (const float*)d_in[16];  // [512,49408]
    const float* ff2_b = (const float*)d_in[17];

    char* ws = (char*)d_ws;
    size_t o = 0;
    auto alloc = [&](size_t bytes) { size_t r = o; o += (bytes + 255) & ~(size_t)255; return r; };

    float*    x     = (float*)   (ws + alloc(4096ull * 512 * 4));
    ushort_t* xb    = (ushort_t*)(ws + alloc(4096ull * 512 * 2));
    float*    tmpf  = (float*)   (ws + alloc(4096ull * 512 * 4));   // img_out
    ushort_t* qkvb  = (ushort_t*)(ws + alloc(4096ull * 1536 * 2));  // [4096][q|k|v]
    ushort_t* Atxt  = (ushort_t*)(ws + alloc(2560ull * 512 * 2));   // fallback only
    ushort_t* Aimg  = (ushort_t*)(ws + alloc(1664ull * 768 * 2));
    ushort_t* wqkvT = (ushort_t*)(ws + alloc(1536ull * 512 * 2));   // [wqT;wkT;wvT]
    ushort_t* ff0T  = (ushort_t*)(ws + alloc(512ull * 768 * 2));
    ushort_t* ff1T  = (ushort_t*)(ws + alloc(512ull * 512 * 2));
    float*    bcat  = (float*)   (ws + alloc(1536 * 4));
    size_t base_bytes = o;
    size_t ff2T_bytes = 49408ull * 512 * 2;                          // 50.6 MB
    bool use_ff2T = (ws_size >= base_bytes + ff2T_bytes + 256);
    ushort_t* ff2T = use_ff2T ? (ushort_t*)(ws + alloc(ff2T_bytes)) : nullptr;

    dim3 b32x8(32, 8);

    transpose_bf3<<<dim3(16, 16, 3), b32x8, 0, stream>>>(wq, wk, wv, wqkvT);
    transpose_bf<<<dim3(16, 24), b32x8, 0, stream>>>(ff0_w, ff0T, 768, 512);
    transpose_bf<<<dim3(16, 16), b32x8, 0, stream>>>(ff1_w, ff1T, 512, 512);
    biascat<<<6, 256, 0, stream>>>(wq_b, wk_b, wv_b, bcat);
    if (use_ff2T)
        transpose_ff2<<<dim3(772, 8), 256, 0, stream>>>(ff2_w, ff2T);
    conv_pad<<<(1664 * 768 + 255) / 256, 256, 0, stream>>>(img, Aimg, 1600, 768, 1664 * 768);

    // ff0: img_out = Aimg @ ff0T^T + ff0_b -> tmpf [1600][512]
    gemm_bf16<0, 0, 0><<<dim3(4, 13, 1), 256, 0, stream>>>(
        Aimg, ff0T, tmpf, nullptr, ff0_b, 768, 768, 768, 512, 0, 0, 0, 1600, 1.f);

    build_x<<<4096, 64, 0, stream>>>(tmpf, cap, tok, pos, ln_g, ln_b, x, xb);

    for (int l = 0; l < 2; l++) {
        // fused qkv: [4096][1536] = xb @ WqkvT^T + bcat   (wv_b included in V)
        gemm_bf16<0, 0, 0><<<dim3(12, 32, 1), 256, 0, stream>>>(
            xb, wqkvT, nullptr, qkvb, bcat, 512, 512, 512, 1536, 0, 0, 0, 4096, 1.f);
        // fused attention + residual-LN: writes x, xb directly
        attn_fused<<<dim3(2, 32), 512, 0, stream>>>(qkvb, x, xb, ln_g, ln_b);
        // fused ff1 + residual-LN: updates x, xb in place
        ff1_fused<<<126, 512, 0, stream>>>(xb, ff1T, ff1_b, x, ln_g, ln_b);
    }

    // logits (f32 out): d_out = gather(xb) @ ff2T^T + ff2_b
    if (use_ff2T) {
        gemm_big<<<dim3(193, 10), 512, 0, stream>>>(
            xb, ff2T, (float*)d_out, ff2_b, 512, 512, 49408, 2432);
    } else {
        gather_txt<<<(2560 * 512 + 255) / 256, 256, 0, stream>>>(xb, Atxt);
        gemm_bf16<1, 1, 0><<<dim3(386, 20, 1), 256, 0, stream>>>(
            Atxt, ff2_w, (float*)d_out, nullptr, ff2_b, 512, 512, 49408, 49408,
            0, 0, 0, 2432, 1.f);
    }
}

// Round 28
// 389.804 us; speedup vs baseline: 1.1222x; 1.0910x over previous
//
#include <hip/hip_runtime.h>

typedef unsigned short ushort_t;
typedef __attribute__((ext_vector_type(8))) short short8;
typedef __attribute__((ext_vector_type(4))) float f32x4;
typedef __attribute__((ext_vector_type(4))) unsigned short bf4;
typedef __attribute__((ext_vector_type(8))) unsigned short bf8v;

__device__ __forceinline__ ushort_t f2bf(float f) {
    union { float f; unsigned u; } v; v.f = f;
    unsigned r = v.u + 0x7FFFu + ((v.u >> 16) & 1u);
    return (ushort_t)(r >> 16);
}

__device__ __forceinline__ void g2lds16(const ushort_t* g, ushort_t* l) {
    __builtin_amdgcn_global_load_lds(
        (const __attribute__((address_space(1))) void*)g,
        (__attribute__((address_space(3))) void*)l, 16, 0, 0);
}

#define LDT 72  // padded LDS row stride (reg-staged paths)

// ---------------------------------------------------------------------------
// gemm_big: logits GEMM (r14 structure + r17 fused text-gather in A-staging).
// r27: bijective XCD-aware block remap (T1/m204) -> B-panels L2-local (-12us).
// r28: non-temporal C stores: 480 MB of never-re-read f32 output marked
// evict-first so it stops evicting the XCD-resident B panels (retry of the
// pre-remap null under the new placement regime; mechanism changed).
// ---------------------------------------------------------------------------
__global__ __launch_bounds__(512) void gemm_big(
    const ushort_t* __restrict__ xb, const ushort_t* __restrict__ B,
    float* __restrict__ C, const float* __restrict__ bias,
    int K, int ldb, int ldc, int validM)
{
    __shared__ __attribute__((aligned(16))) ushort_t As[2][256 * 64];
    __shared__ __attribute__((aligned(16))) ushort_t Bs[2][256 * 64];

    const int tid = threadIdx.x;
    const int lane = tid & 63;
    const int wave = tid >> 6;       // 0..7
    const int wr = wave >> 2;        // 0..1 : 128-row band
    const int wc = wave & 3;         // 0..3 : 64-col slice
    int tN, tM;
    {
        const int lin0 = blockIdx.x + blockIdx.y * gridDim.x;
        const int nwg = gridDim.x * gridDim.y;
        // bijective XCD remap (m204): XCD (= lin0 & 7 dispatch round-robin)
        // owns a contiguous logical range.
        const int q = nwg >> 3, r = nwg & 7;
        const int xcd = lin0 & 7;
        const int lin = (xcd < r ? xcd * (q + 1)
                                 : r * (q + 1) + (xcd - r) * q) + (lin0 >> 3);
        const int TM = gridDim.y;
        const int full = gridDim.x >> 3;
        const int per = TM << 3;
        const int g = lin / per;
        if (g < full) {
            const int rem = lin - g * per;
            tM = rem >> 3;
            tN = (g << 3) + (rem & 7);
        } else {
            const int rem = lin - full * per;
            const int w = gridDim.x - (full << 3);
            tM = rem / w;
            tN = (full << 3) + rem - tM * w;
        }
    }
    const int n0 = tN * 256;
    const ushort_t* Bbase = B + (long)n0 * ldb;

    f32x4 acc[8][4];
#pragma unroll
    for (int m = 0; m < 8; m++)
#pragma unroll
        for (int n = 0; n < 4; n++) acc[m][n] = (f32x4)0.f;

    auto STAGE = [&](int buf, int ks) {
#pragma unroll
        for (int i = 0; i < 4; i++) {
            int ch = i * 512 + tid;
            int row = ch >> 3, c16 = ch & 7;
            int c16s = c16 ^ (row & 7);
            int gr = tM * 256 + row;
            if (gr > 2431) gr = 2431;            // masked by validM at store
            int bb = gr / 76;
            int xrow = bb * 126 + 50 + (gr - bb * 76);
            g2lds16(xb + (long)xrow * 512 + ks + (c16s << 3),
                    &As[buf][(i * 512 + wave * 64) * 8]);
        }
#pragma unroll
        for (int i = 0; i < 4; i++) {
            int ch = i * 512 + tid;
            int row = ch >> 3, c16 = ch & 7;
            int c16s = c16 ^ (row & 7);
            g2lds16(Bbase + (long)row * ldb + ks + (c16s << 3),
                    &Bs[buf][(i * 512 + wave * 64) * 8]);
        }
    };

    const int nt = K >> 6;
    STAGE(0, 0);
    for (int t = 0; t < nt; ++t) {
        if (t + 1 < nt) {
            STAGE((t + 1) & 1, (t + 1) << 6);
            asm volatile("s_waitcnt vmcnt(8)" ::: "memory");   // tile t done
        } else {
            asm volatile("s_waitcnt vmcnt(0)" ::: "memory");
        }
        asm volatile("s_barrier" ::: "memory");

        const ushort_t* Ac = As[t & 1];
        const ushort_t* Bc = Bs[t & 1];
        __builtin_amdgcn_s_setprio(1);
#pragma unroll
        for (int ksub = 0; ksub < 2; ksub++) {
            const int kk = ksub * 32 + ((lane >> 4) << 3);
            const int kc = kk >> 3;
            short8 af[8], bfr[4];
#pragma unroll
            for (int m = 0; m < 8; m++) {
                const int r = (wr << 7) + m * 16 + (lane & 15);
                af[m] = *(const short8*)(Ac + r * 64 + ((kc ^ (r & 7)) << 3));
            }
#pragma unroll
            for (int n = 0; n < 4; n++) {
                const int r = (wc << 6) + n * 16 + (lane & 15);
                bfr[n] = *(const short8*)(Bc + r * 64 + ((kc ^ (r & 7)) << 3));
            }
#pragma unroll
            for (int m = 0; m < 8; m++)
#pragma unroll
                for (int n = 0; n < 4; n++)
                    acc[m][n] = __builtin_amdgcn_mfma_f32_16x16x32_bf16(
                        af[m], bfr[n], acc[m][n], 0, 0, 0);
        }
        __builtin_amdgcn_s_setprio(0);
        asm volatile("s_barrier" ::: "memory");
    }

    const int rb = (wr << 7) + ((lane >> 4) << 2);
    const int cb = (wc << 6) + (lane & 15);
#pragma unroll
    for (int m = 0; m < 8; m++) {
#pragma unroll
        for (int i = 0; i < 4; i++) {
            int r = tM * 256 + rb + m * 16 + i;
            if (r >= validM) continue;
#pragma unroll
            for (int n = 0; n < 4; n++) {
                int cg = n0 + cb + n * 16;
                __builtin_nontemporal_store(acc[m][n][i] + bias[cg],
                                            &C[(long)r * ldc + cg]);
            }
        }
    }
}

// ---------------------------------------------------------------------------
// ff1_fused: y = LN(x + xb@ff1T^T + ff1_b) in place (r20, validated).
// ---------------------------------------------------------------------------
__global__ __launch_bounds__(512) void ff1_fused(
    ushort_t* __restrict__ xbg, const ushort_t* __restrict__ ff1T,
    const float* __restrict__ bias, float* __restrict__ xg,
    const float* __restrict__ ln_g, const float* __restrict__ ln_b)
{
    __shared__ __attribute__((aligned(16))) ushort_t As[32 * 64];    // 4 KB
    __shared__ __attribute__((aligned(16))) ushort_t Bs[512 * 64];   // 64 KB
    __shared__ float redm[4 * 32];
    __shared__ float reds[4 * 32];

    const int tid = threadIdx.x;
    const int lane = tid & 63;
    const int wave = tid >> 6;
    const int wr = wave >> 2;     // 0..1 : 16-row band
    const int wc = wave & 3;      // 0..3 : 128-col slice
    const int r0 = blockIdx.x << 5;   // 32 rows/block, 126 blocks, all valid

    f32x4 acc[8];
#pragma unroll
    for (int n = 0; n < 8; n++) acc[n] = (f32x4)0.f;

    auto STAGE = [&](int ks) {
        // chunk space: A = 256 chunks (32x64), B = 4096 chunks (512x64)
#pragma unroll
        for (int i = 0; i < 9; i++) {
            int cb = i * 512 + wave * 64;       // wave-uniform chunk base
            if (cb >= 4352) continue;
            int ch = cb + lane;
            if (cb < 256) {                     // A chunk
                int row = ch >> 3, c16 = ch & 7;
                int c16s = c16 ^ (row & 7);
                g2lds16(xbg + (long)(r0 + row) * 512 + ks + (c16s << 3),
                        &As[cb * 8]);
            } else {                            // B chunk
                int bch = ch - 256;
                int row = bch >> 3, c16 = bch & 7;
                int c16s = c16 ^ (row & 7);
                g2lds16(ff1T + (long)row * 512 + ks + (c16s << 3),
                        &Bs[(cb - 256) * 8]);
            }
        }
    };

    for (int ks = 0; ks < 512; ks += 64) {
        if (ks) asm volatile("s_barrier" ::: "memory");  // prev readers done
        STAGE(ks);
        asm volatile("s_waitcnt vmcnt(0)" ::: "memory");
        asm volatile("s_barrier" ::: "memory");

        __builtin_amdgcn_s_setprio(1);
#pragma unroll
        for (int ksub = 0; ksub < 2; ksub++) {
            const int kc = ksub * 4 + (lane >> 4);
            short8 af;
            {
                const int r = (wr << 4) + (lane & 15);
                af = *(const short8*)(As + r * 64 + ((kc ^ (r & 7)) << 3));
            }
            short8 bfr[8];
#pragma unroll
            for (int n = 0; n < 8; n++) {
                const int r = (wc << 7) + n * 16 + (lane & 15);
                bfr[n] = *(const short8*)(Bs + r * 64 + ((kc ^ (r & 7)) << 3));
            }
#pragma unroll
            for (int n = 0; n < 8; n++)
                acc[n] = __builtin_amdgcn_mfma_f32_16x16x32_bf16(
                    af, bfr[n], acc[n], 0, 0, 0);
        }
        __builtin_amdgcn_s_setprio(0);
    }

    // ---- epilogue: bias + residual + LayerNorm ----
    float gg[8], bb2[8], bi[8];
#pragma unroll
    for (int n = 0; n < 8; n++) {
        int d = (wc << 7) + n * 16 + (lane & 15);
        gg[n] = ln_g[d];
        bb2[n] = ln_b[d];
        bi[n] = bias[d];
    }
    float vv[4][8];
#pragma unroll
    for (int i = 0; i < 4; i++) {
        const int rl = (wr << 4) + ((lane >> 4) << 2) + i;
        const long xrow = (long)(r0 + rl) << 9;
        float s = 0.f, sq = 0.f;
#pragma unroll
        for (int n = 0; n < 8; n++) {
            int d = (wc << 7) + n * 16 + (lane & 15);
            float v = acc[n][i] + bi[n] + xg[xrow + d];
            vv[i][n] = v;
            s += v; sq += v * v;
        }
#pragma unroll
        for (int o = 8; o >= 1; o >>= 1) { s += __shfl_xor(s, o); sq += __shfl_xor(sq, o); }
        if ((lane & 15) == 0) {
            redm[wc * 32 + rl] = s;
            reds[wc * 32 + rl] = sq;
        }
    }
    __syncthreads();
#pragma unroll
    for (int i = 0; i < 4; i++) {
        const int rl = (wr << 4) + ((lane >> 4) << 2) + i;
        float S = redm[rl] + redm[32 + rl] + redm[64 + rl] + redm[96 + rl];
        float SQ = reds[rl] + reds[32 + rl] + reds[64 + rl] + reds[96 + rl];
        float mean = S * (1.f / 512.f);
        float var = SQ * (1.f / 512.f) - mean * mean;
        float inv = rsqrtf(var + 1e-5f);
        const long xrow = (long)(r0 + rl) << 9;
#pragma unroll
        for (int n = 0; n < 8; n++) {
            int d = (wc << 7) + n * 16 + (lane & 15);
            float y = (vv[i][n] - mean) * inv * gg[n] + bb2[n];
            xg[xrow + d] = y;
            xbg[xrow + d] = f2bf(y);
        }
    }
}

// ---------------------------------------------------------------------------
// attn_fused: QK^T + softmax + PV + residual-LN (r18, validated).
// ---------------------------------------------------------------------------
__global__ __launch_bounds__(512) void attn_fused(
    const ushort_t* __restrict__ qkv, float* __restrict__ xg,
    ushort_t* __restrict__ xbg, const float* __restrict__ ln_g,
    const float* __restrict__ ln_b)
{
    __shared__ __attribute__((aligned(16))) ushort_t smem[41984];
    ushort_t* Vs = smem;                      // [512][64]   (phase 3)
    ushort_t* Ps = smem + 32768;              // [64][128]
    float* redm = (float*)(smem + 40960);     // [4][64]
    float* reds = redm + 256;                 // [4][64]
    ushort_t* Qs = smem;                      // [2][64*64]  (phase 1)
    ushort_t* Ks = smem + 8192;               // [2][128*64]

    const int tid = threadIdx.x;
    const int lane = tid & 63;
    const int wave = tid >> 6;
    const int wr = wave >> 2;     // 0..1
    const int wc = wave & 3;      // 0..3
    const int qh = blockIdx.x;    // 0..1
    const int b  = blockIdx.y;    // 0..31
    const long qbase = ((long)(b * 126) + qh * 64) * 1536;
    const long kbase = (long)(b * 126) * 1536 + 512;
    const long vbase = (long)(b * 126) * 1536 + 1024;
    const float rsqd = 0.044194173824159216f;

    // ================= phase 1: S = Q K^T =================
    f32x4 acc[2][2];
#pragma unroll
    for (int m = 0; m < 2; m++)
#pragma unroll
        for (int n = 0; n < 2; n++) acc[m][n] = (f32x4)0.f;

    auto SQK = [&](int buf, int ks) {
        {   // Q tile 64x64: 512 chunks, 1/thread
            int ch = tid;
            int row = ch >> 3, c16 = ch & 7;
            int c16s = c16 ^ (row & 7);
            g2lds16(qkv + qbase + (long)row * 1536 + ks + (c16s << 3),
                    Qs + buf * 4096 + (wave * 64) * 8);
        }
#pragma unroll
        for (int i = 0; i < 2; i++) {  // K tile 128x64: 1024 chunks
            int ch = i * 512 + tid;
            int row = ch >> 3, c16 = ch & 7;
            int c16s = c16 ^ (row & 7);
            g2lds16(qkv + kbase + (long)row * 1536 + ks + (c16s << 3),
                    Ks + buf * 8192 + (i * 512 + wave * 64) * 8);
        }
    };

    SQK(0, 0);
    for (int t = 0; t < 8; ++t) {
        if (t < 7) {
            SQK((t + 1) & 1, (t + 1) << 6);
            asm volatile("s_waitcnt vmcnt(3)" ::: "memory");
        } else {
            asm volatile("s_waitcnt vmcnt(0)" ::: "memory");
        }
        asm volatile("s_barrier" ::: "memory");
        const ushort_t* Qc = Qs + (t & 1) * 4096;
        const ushort_t* Kc = Ks + (t & 1) * 8192;
#pragma unroll
        for (int ksub = 0; ksub < 2; ksub++) {
            const int kc = ksub * 4 + (lane >> 4);
            short8 af[2], bfr[2];
#pragma unroll
            for (int m = 0; m < 2; m++) {
                const int r = (wr << 5) + m * 16 + (lane & 15);
                af[m] = *(const short8*)(Qc + r * 64 + ((kc ^ (r & 7)) << 3));
            }
#pragma unroll
            for (int n = 0; n < 2; n++) {
                const int r = (wc << 5) + n * 16 + (lane & 15);
                bfr[n] = *(const short8*)(Kc + r * 64 + ((kc ^ (r & 7)) << 3));
            }
#pragma unroll
            for (int m = 0; m < 2; m++)
#pragma unroll
                for (int n = 0; n < 2; n++)
                    acc[m][n] = __builtin_amdgcn_mfma_f32_16x16x32_bf16(
                        af[m], bfr[n], acc[m][n], 0, 0, 0);
        }
        asm volatile("s_barrier" ::: "memory");
    }

    // ================= phase 2: masked softmax =================
    float rm[2][4];
#pragma unroll
    for (int m = 0; m < 2; m++) {
#pragma unroll
        for (int i = 0; i < 4; i++) {
            const int rl = (wr << 5) + m * 16 + ((lane >> 4) << 2) + i;
            const int q = qh * 64 + rl;
            float mx = -3.0e38f;
#pragma unroll
            for (int n = 0; n < 2; n++) {
                int j = (wc << 5) + n * 16 + (lane & 15);
                bool ok = (j < 126) && ((j < 50) || (j <= q));
                float s = acc[m][n][i] * rsqd;
                acc[m][n][i] = ok ? s : -3.0e38f;
                if (ok) mx = fmaxf(mx, s);
            }
#pragma unroll
            for (int o = 8; o >= 1; o >>= 1) mx = fmaxf(mx, __shfl_xor(mx, o));
            rm[m][i] = mx;
        }
    }
    if ((lane & 15) == 0) {
#pragma unroll
        for (int m = 0; m < 2; m++)
#pragma unroll
            for (int i = 0; i < 4; i++) {
                int rl = (wr << 5) + m * 16 + ((lane >> 4) << 2) + i;
                redm[wc * 64 + rl] = rm[m][i];
            }
    }
    __syncthreads();
    float rs[2][4];
#pragma unroll
    for (int m = 0; m < 2; m++) {
#pragma unroll
        for (int i = 0; i < 4; i++) {
            const int rl = (wr << 5) + m * 16 + ((lane >> 4) << 2) + i;
            float M = fmaxf(fmaxf(redm[rl], redm[64 + rl]),
                            fmaxf(redm[128 + rl], redm[192 + rl]));
            float sum = 0.f;
#pragma unroll
            for (int n = 0; n < 2; n++) {
                float s = acc[m][n][i];
                float e = (s > -1.0e37f) ? expf(s - M) : 0.f;
                acc[m][n][i] = e;
                sum += e;
            }
#pragma unroll
            for (int o = 8; o >= 1; o >>= 1) sum += __shfl_xor(sum, o);
            rs[m][i] = sum;
        }
    }
    if ((lane & 15) == 0) {
#pragma unroll
        for (int m = 0; m < 2; m++)
#pragma unroll
            for (int i = 0; i < 4; i++) {
                int rl = (wr << 5) + m * 16 + ((lane >> 4) << 2) + i;
                reds[wc * 64 + rl] = rs[m][i];
            }
    }
    __syncthreads();
#pragma unroll
    for (int m = 0; m < 2; m++) {
#pragma unroll
        for (int i = 0; i < 4; i++) {
            const int rl = (wr << 5) + m * 16 + ((lane >> 4) << 2) + i;
            float S = reds[rl] + reds[64 + rl] + reds[128 + rl] + reds[192 + rl];
            float inv = 1.f / S;
#pragma unroll
            for (int n = 0; n < 2; n++) {
                int j = (wc << 5) + n * 16 + (lane & 15);
                int c = j >> 3;
                Ps[rl * 128 + ((c ^ (rl & 7)) << 3) + (j & 7)] =
                    f2bf(acc[m][n][i] * inv);
            }
        }
    }
    __syncthreads();

    // ================= phase 3: attn = P V =================
    f32x4 po[2][8];
#pragma unroll
    for (int m = 0; m < 2; m++)
#pragma unroll
        for (int n = 0; n < 8; n++) po[m][n] = (f32x4)0.f;

    for (int jc = 0; jc < 2; jc++) {
#pragma unroll
        for (int q8 = 0; q8 < 16; q8++) {
            int qid = q8 * 512 + tid;           // 0..8191
            int d = qid & 511, jq = qid >> 9;   // jq 0..15
            const ushort_t* vp = qkv + vbase + (long)(jc * 64 + jq * 4) * 1536 + d;
            bf4 p;
            p[0] = vp[0];
            p[1] = vp[1536];
            p[2] = vp[3072];
            p[3] = vp[4608];
            *(bf4*)(Vs + d * 64 + (((jq >> 1) ^ (d & 7)) << 3) + ((jq & 1) << 2)) = p;
        }
        __syncthreads();
#pragma unroll
        for (int ksub = 0; ksub < 2; ksub++) {
            const int kc = ksub * 4 + (lane >> 4);
            short8 af[2], bv[8];
#pragma unroll
            for (int m = 0; m < 2; m++) {
                const int r = (wr << 5) + m * 16 + (lane & 15);
                const int c = jc * 8 + kc;
                af[m] = *(const short8*)(Ps + r * 128 + ((c ^ (r & 7)) << 3));
            }
#pragma unroll
            for (int n = 0; n < 8; n++) {
                const int r = (wc << 7) + n * 16 + (lane & 15);
                bv[n] = *(const short8*)(Vs + r * 64 + ((kc ^ (r & 7)) << 3));
            }
#pragma unroll
            for (int m = 0; m < 2; m++)
#pragma unroll
                for (int n = 0; n < 8; n++)
                    po[m][n] = __builtin_amdgcn_mfma_f32_16x16x32_bf16(
                        af[m], bv[n], po[m][n], 0, 0, 0);
        }
        __syncthreads();
    }

    // ========= phase 4: residual + LayerNorm -> x, xb =========
    float gg[8], bb2[8];
#pragma unroll
    for (int n = 0; n < 8; n++) {
        int d = (wc << 7) + n * 16 + (lane & 15);
        gg[n] = ln_g[d];
        bb2[n] = ln_b[d];
    }
#pragma unroll
    for (int m = 0; m < 2; m++) {
#pragma unroll
        for (int i = 0; i < 4; i++) {
            const int rl = (wr << 5) + m * 16 + ((lane >> 4) << 2) + i;
            const int q = qh * 64 + rl;
            const long xrow = ((long)(b * 126 + q)) << 9;   // q>=126: pad row, zeroed
            float s = 0.f, sq = 0.f;
#pragma unroll
            for (int n = 0; n < 8; n++) {
                int d = (wc << 7) + n * 16 + (lane & 15);
                float v = po[m][n][i] + xg[xrow + d];
                po[m][n][i] = v;
                s += v; sq += v * v;
            }
#pragma unroll
            for (int o = 8; o >= 1; o >>= 1) { s += __shfl_xor(s, o); sq += __shfl_xor(sq, o); }
            if ((lane & 15) == 0) {
                redm[wc * 64 + rl] = s;
                reds[wc * 64 + rl] = sq;
            }
        }
    }
    __syncthreads();
#pragma unroll
    for (int m = 0; m < 2; m++) {
#pragma unroll
        for (int i = 0; i < 4; i++) {
            const int rl = (wr << 5) + m * 16 + ((lane >> 4) << 2) + i;
            const int q = qh * 64 + rl;
            if (q >= 126) continue;
            float S = redm[rl] + redm[64 + rl] + redm[128 + rl] + redm[192 + rl];
            float SQ = reds[rl] + reds[64 + rl] + reds[128 + rl] + reds[192 + rl];
            float mean = S * (1.f / 512.f);
            float var = SQ * (1.f / 512.f) - mean * mean;
            float inv = rsqrtf(var + 1e-5f);
            const long xrow = ((long)(b * 126 + q)) << 9;
#pragma unroll
            for (int n = 0; n < 8; n++) {
                int d = (wc << 7) + n * 16 + (lane & 15);
                float y = (po[m][n][i] - mean) * inv * gg[n] + bb2[n];
                xg[xrow + d] = y;
                xbg[xrow + d] = f2bf(y);
            }
        }
    }
}

// ---------------------------------------------------------------------------
// Batched bf16 GEMM (128x128): BSRC=0 dbuf + counted vmcnt; BSRC=1 reg-staged
// fallback (validated).
// ---------------------------------------------------------------------------
template <int BSRC, int SWZ, int NT>
__global__ __launch_bounds__(256) void gemm_bf16(
    const ushort_t* __restrict__ A, const void* __restrict__ Bv,
    float* __restrict__ C, ushort_t* __restrict__ Cb,
    const float* __restrict__ bias,
    int K, int lda, int ldb, int ldc,
    long sA, long sB, long sC,
    int validM, float scale)
{
    constexpr int LS = (BSRC == 0) ? 64 : LDT;
    constexpr int NBUF = (BSRC == 0) ? 2 : 1;
    __shared__ __attribute__((aligned(16))) ushort_t As[NBUF * 128 * LS];
    __shared__ __attribute__((aligned(16))) ushort_t Bs[NBUF * 128 * LS];

    const int tid = threadIdx.x;
    const int lane = tid & 63;
    const int wave = tid >> 6;
    const int wr = wave >> 1, wc = wave & 1;
    int tN = blockIdx.x, tM = blockIdx.y;
    const int bz = blockIdx.z;
    if (SWZ) {
        const int lin = blockIdx.x + blockIdx.y * gridDim.x;
        const int TM = gridDim.y;
        const int full = gridDim.x >> 3;
        const int per = TM << 3;
        const int g = lin / per;
        if (g < full) {
            const int rem = lin - g * per;
            tM = rem >> 3;
            tN = (g << 3) + (rem & 7);
        } else {
            const int rem = lin - full * per;
            const int w = gridDim.x - (full << 3);
            tM = rem / w;
            tN = (full << 3) + rem - tM * w;
        }
    }
    const int n0 = tN * 128;

    const ushort_t* Abase = A + (long)bz * sA + (long)tM * 128 * lda;
    const ushort_t* Bb = (BSRC == 0)
        ? (const ushort_t*)Bv + (long)bz * sB + (long)n0 * ldb : nullptr;
    const float* Bf = (BSRC == 1)
        ? (const float*)Bv + (long)bz * sB : nullptr;

    f32x4 acc[4][4];
#pragma unroll
    for (int m = 0; m < 4; m++)
#pragma unroll
        for (int n = 0; n < 4; n++) acc[m][n] = (f32x4)0.f;

    if (BSRC == 0) {
        auto STAGE = [&](int buf, int ks) {
            ushort_t* Ad = As + buf * (128 * 64);
            ushort_t* Bd = Bs + buf * (128 * 64);
#pragma unroll
            for (int i = 0; i < 4; i++) {
                int ch = wave * 256 + i * 64 + lane;
                int row = ch >> 3, c16 = ch & 7;
                int c16s = c16 ^ (row & 7);
                g2lds16(Abase + (long)row * lda + ks + (c16s << 3),
                        Ad + (wave * 256 + i * 64) * 8);
            }
#pragma unroll
            for (int i = 0; i < 4; i++) {
                int ch = wave * 256 + i * 64 + lane;
                int row = ch >> 3, c16 = ch & 7;
                int c16s = c16 ^ (row & 7);
                g2lds16(Bb + (long)row * ldb + ks + (c16s << 3),
                        Bd + (wave * 256 + i * 64) * 8);
            }
        };

        const int nt = K >> 6;
        STAGE(0, 0);
        for (int t = 0; t < nt; ++t) {
            if (t + 1 < nt) {
                STAGE((t + 1) & 1, (t + 1) << 6);
                asm volatile("s_waitcnt vmcnt(8)" ::: "memory");
            } else {
                asm volatile("s_waitcnt vmcnt(0)" ::: "memory");
            }
            asm volatile("s_barrier" ::: "memory");

            const ushort_t* Ac = As + (t & 1) * (128 * 64);
            const ushort_t* Bc = Bs + (t & 1) * (128 * 64);
#pragma unroll
            for (int ksub = 0; ksub < 2; ksub++) {
                const int kk = ksub * 32 + ((lane >> 4) << 3);
                const int kc = kk >> 3;
                short8 af[4], bfr[4];
#pragma unroll
                for (int m = 0; m < 4; m++) {
                    const int r = (wr << 6) + m * 16 + (lane & 15);
                    af[m] = *(const short8*)(Ac + r * 64 + ((kc ^ (r & 7)) << 3));
                }
#pragma unroll
                for (int n = 0; n < 4; n++) {
                    const int r = (wc << 6) + n * 16 + (lane & 15);
                    bfr[n] = *(const short8*)(Bc + r * 64 + ((kc ^ (r & 7)) << 3));
                }
#pragma unroll
                for (int m = 0; m < 4; m++)
#pragma unroll
                    for (int n = 0; n < 4; n++)
                        acc[m][n] = __builtin_amdgcn_mfma_f32_16x16x32_bf16(
                            af[m], bfr[n], acc[m][n], 0, 0, 0);
            }
            asm volatile("s_barrier" ::: "memory");
        }
    } else {
        for (int ks = 0; ks < K; ks += 64) {
            short8 ar[4];
#pragma unroll
            for (int i = 0; i < 4; i++) {
                int ch = wave * 256 + i * 64 + lane;
                int row = ch >> 3, c16 = ch & 7;
                ar[i] = *(const short8*)(Abase + (long)row * lda + ks + (c16 << 3));
            }
            bf4 pk[8];
#pragma unroll
            for (int q = 0; q < 8; q++) {
                int qid = q * 256 + tid;
                int n = qid & 127, kq = qid >> 7;
                const float* wp = Bf + (long)(ks + kq * 4) * ldb + n0 + n;
                bf4 p;
                p[0] = f2bf(wp[0]);
                p[1] = f2bf(wp[ldb]);
                p[2] = f2bf(wp[2 * (long)ldb]);
                p[3] = f2bf(wp[3 * (long)ldb]);
                pk[q] = p;
            }
            if (ks) __syncthreads();
#pragma unroll
            for (int i = 0; i < 4; i++) {
                int ch = wave * 256 + i * 64 + lane;
                int row = ch >> 3, c16 = ch & 7;
                *(short8*)(As + row * LS + (c16 << 3)) = ar[i];
            }
#pragma unroll
            for (int q = 0; q < 8; q++) {
                int qid = q * 256 + tid;
                int n = qid & 127, kq = qid >> 7;
                *(bf4*)(Bs + n * LS + (kq << 2)) = pk[q];
            }
            __syncthreads();

#pragma unroll
            for (int ksub = 0; ksub < 2; ksub++) {
                const int kk = ksub * 32 + ((lane >> 4) << 3);
                short8 af[4], bfr[4];
#pragma unroll
                for (int m = 0; m < 4; m++) {
                    const int r = (wr << 6) + m * 16 + (lane & 15);
                    af[m] = *(const short8*)(As + r * LS + kk);
                }
#pragma unroll
                for (int n = 0; n < 4; n++) {
                    const int r = (wc << 6) + n * 16 + (lane & 15);
                    bfr[n] = *(const short8*)(Bs + r * LS + kk);
                }
#pragma unroll
                for (int m = 0; m < 4; m++)
#pragma unroll
                    for (int n = 0; n < 4; n++)
                        acc[m][n] = __builtin_amdgcn_mfma_f32_16x16x32_bf16(
                            af[m], bfr[n], acc[m][n], 0, 0, 0);
            }
            if (ks + 64 < K) __syncthreads();
        }
    }

    const int rb = (wr << 6) + ((lane >> 4) << 2);
    const int cb = (wc << 6) + (lane & 15);
#pragma unroll
    for (int m = 0; m < 4; m++) {
#pragma unroll
        for (int i = 0; i < 4; i++) {
            int r = tM * 128 + rb + m * 16 + i;
            if (r >= validM) continue;
#pragma unroll
            for (int n = 0; n < 4; n++) {
                int cg = n0 + cb + n * 16;
                float v = acc[m][n][i] * scale + (bias ? bias[cg] : 0.f);
                long off = (long)bz * sC + (long)r * ldc + cg;
                if (C) {
                    if (NT) __builtin_nontemporal_store(v, &C[off]);
                    else    C[off] = v;
                }
                if (Cb) Cb[off] = f2bf(v);
            }
        }
    }
}

// ---------------------------------------------------------------------------
// transpose f32 [R][C] -> bf16 [C][R]   (small weights)
// ---------------------------------------------------------------------------
__global__ __launch_bounds__(256) void transpose_bf(
    const float* __restrict__ in, ushort_t* __restrict__ out, int R, int C)
{
    __shared__ float t[32][33];
    int c0 = blockIdx.x << 5, r0 = blockIdx.y << 5;
    int tx = threadIdx.x, ty = threadIdx.y;
#pragma unroll
    for (int i = 0; i < 4; i++)
        t[ty + i * 8][tx] = in[(long)(r0 + ty + i * 8) * C + c0 + tx];
    __syncthreads();
#pragma unroll
    for (int i = 0; i < 4; i++)
        out[(long)(c0 + ty + i * 8) * R + r0 + tx] = f2bf(t[tx][ty + i * 8]);
}

// wide 64x64-tile transpose for ff2 (r21, validated).
__global__ __launch_bounds__(256) void transpose_ff2(
    const float* __restrict__ in, ushort_t* __restrict__ out)
{
    __shared__ float t[64][65];
    const int c0 = blockIdx.x << 6;   // input col base, 772 blocks
    const int r0 = blockIdx.y << 6;   // input row base, 8 blocks
    const int tx = threadIdx.x & 63, ty = threadIdx.x >> 6;  // 64 x 4
#pragma unroll
    for (int i = 0; i < 16; i++) {
        int r = ty + i * 4;
        t[r][tx] = in[(long)(r0 + r) * 49408 + c0 + tx];
    }
    __syncthreads();
#pragma unroll
    for (int i = 0; i < 16; i++) {
        int r = ty + i * 4;           // output row within tile = input col
        out[(long)(c0 + r) * 512 + r0 + tx] = f2bf(t[tx][r]);
    }
}

// merged 512x512 transpose x3 (wq,wk,wv -> wqkvT), grid (16,16,3)
__global__ __launch_bounds__(256) void transpose_bf3(
    const float* __restrict__ s0, const float* __restrict__ s1,
    const float* __restrict__ s2, ushort_t* __restrict__ out)
{
    __shared__ float t[32][33];
    const float* in = (blockIdx.z == 0) ? s0 : (blockIdx.z == 1) ? s1 : s2;
    ushort_t* o = out + (long)blockIdx.z * 512 * 512;
    int c0 = blockIdx.x << 5, r0 = blockIdx.y << 5;
    int tx = threadIdx.x, ty = threadIdx.y;
#pragma unroll
    for (int i = 0; i < 4; i++)
        t[ty + i * 8][tx] = in[(long)(r0 + ty + i * 8) * 512 + c0 + tx];
    __syncthreads();
#pragma unroll
    for (int i = 0; i < 4; i++)
        o[(long)(c0 + ty + i * 8) * 512 + r0 + tx] = f2bf(t[tx][ty + i * 8]);
}

// concat 3 x [512] f32 bias vectors
__global__ __launch_bounds__(256) void biascat(
    const float* __restrict__ b0, const float* __restrict__ b1,
    const float* __restrict__ b2, float* __restrict__ out)
{
    int i = blockIdx.x * 256 + threadIdx.x;  // [0,1536)
    const float* s = (i < 512) ? b0 : (i < 1024) ? b1 : b2;
    out[i] = s[i & 511];
}

// f32 [validR][C] -> bf16 [Rpad][C] with zero pad
__global__ __launch_bounds__(256) void conv_pad(
    const float* __restrict__ in, ushort_t* __restrict__ out,
    int validR, int C, int total)
{
    int idx = blockIdx.x * 256 + threadIdx.x;
    if (idx >= total) return;
    int r = idx / C;
    float v = 0.f;
    if (r < validR) v = in[idx];
    out[idx] = f2bf(v);
}

// gather final-LN bf16 rows for txt positions -> Atxt (fallback path only)
__global__ __launch_bounds__(256) void gather_txt(
    const ushort_t* __restrict__ xb, ushort_t* __restrict__ At)
{
    int idx = blockIdx.x * 256 + threadIdx.x;
    if (idx >= 2560 * 512) return;
    int r = idx >> 9, c = idx & 511;
    if (r < 2432) {
        int b = r / 76, t = r - b * 76;
        At[idx] = xb[((long)(b * 126 + 50 + t) << 9) + c];
    } else {
        At[idx] = 0;
    }
}

// build x = LN(concat(img_out, tok_emb[cap]+pos)) ; rows >= 4032 zeroed
__global__ __launch_bounds__(64) void build_x(
    const float* __restrict__ imgout, const int* __restrict__ cap,
    const float* __restrict__ tok, const float* __restrict__ pos,
    const float* __restrict__ g, const float* __restrict__ bb,
    float* __restrict__ x, ushort_t* __restrict__ xb)
{
    int r = blockIdx.x, lane = threadIdx.x;
    int c0 = lane << 3;
    long base = ((long)r << 9) + c0;
    if (r >= 4032) {
        *(f32x4*)(x + base) = (f32x4)0.f;
        *(f32x4*)(x + base + 4) = (f32x4)0.f;
        *(bf8v*)(xb + base) = (bf8v)0;
        return;
    }
    int b = r / 126, s = r - b * 126;
    float v[8];
    if (s < 50) {
        const float* src = imgout + ((long)(b * 50 + s) << 9) + c0;
        f32x4 a0 = *(const f32x4*)src, a1 = *(const f32x4*)(src + 4);
#pragma unroll
        for (int i = 0; i < 4; i++) { v[i] = a0[i]; v[4 + i] = a1[i]; }
    } else {
        int t = s - 50;
        int id = cap[b * 76 + t];
        const float* s1 = tok + ((long)id << 9) + c0;
        const float* s2 = pos + ((long)t << 9) + c0;
        f32x4 a0 = *(const f32x4*)s1, a1 = *(const f32x4*)(s1 + 4);
        f32x4 b0 = *(const f32x4*)s2, b1 = *(const f32x4*)(s2 + 4);
#pragma unroll
        for (int i = 0; i < 4; i++) { v[i] = a0[i] + b0[i]; v[4 + i] = a1[i] + b1[i]; }
    }
    float sum = 0.f, sq = 0.f;
#pragma unroll
    for (int i = 0; i < 8; i++) { sum += v[i]; sq += v[i] * v[i]; }
#pragma unroll
    for (int o = 32; o >= 1; o >>= 1) { sum += __shfl_xor(sum, o); sq += __shfl_xor(sq, o); }
    float mean = sum * (1.f / 512.f);
    float var = sq * (1.f / 512.f) - mean * mean;
    float inv = rsqrtf(var + 1e-5f);
    bf8v ob;
#pragma unroll
    for (int i = 0; i < 8; i++) {
        float y = (v[i] - mean) * inv * g[c0 + i] + bb[c0 + i];
        x[base + i] = y;
        ob[i] = f2bf(y);
    }
    *(bf8v*)(xb + base) = ob;
}

// ---------------------------------------------------------------------------
extern "C" void kernel_launch(void* const* d_in, const int* in_sizes, int n_in,
                              void* d_out, int out_size, void* d_ws, size_t ws_size,
                              hipStream_t stream)
{
    const float* img   = (const float*)d_in[0];   // [32,50,768]
    const int*   cap   = (const int*)  d_in[1];   // [32,76]
    const float* tok   = (const float*)d_in[2];   // [49408,512]
    const float* pos   = (const float*)d_in[3];   // [76,512]
    const float* ff0_w = (const float*)d_in[4];   // [768,512]
    const float* ff0_b = (const float*)d_in[5];
    const float* wq    = (const float*)d_in[6];
    const float* wq_b  = (const float*)d_in[7];
    const float* wk    = (const float*)d_in[8];
    const float* wk_b  = (const float*)d_in[9];
    const float* wv    = (const float*)d_in[10];
    const float* wv_b  = (const float*)d_in[11];
    const float* ln_g  = (const float*)d_in[12];
    const float* ln_b  = (const float*)d_in[13];
    const float* ff1_w = (const float*)d_in[14];
    const float* ff1_b = (const float*)d_in[15];
    const float* ff2_w = (const float*)d_in[16];  // [512,49408]
    const float* ff2_b = (const float*)d_in[17];

    char* ws = (char*)d_ws;
    size_t o = 0;
    auto alloc = [&](size_t bytes) { size_t r = o; o += (bytes + 255) & ~(size_t)255; return r; };

    float*    x     = (float*)   (ws + alloc(4096ull * 512 * 4));
    ushort_t* xb    = (ushort_t*)(ws + alloc(4096ull * 512 * 2));
    float*    tmpf  = (float*)   (ws + alloc(4096ull * 512 * 4));   // img_out
    ushort_t* qkvb  = (ushort_t*)(ws + alloc(4096ull * 1536 * 2));  // [4096][q|k|v]
    ushort_t* Atxt  = (ushort_t*)(ws + alloc(2560ull * 512 * 2));   // fallback only
    ushort_t* Aimg  = (ushort_t*)(ws + alloc(1664ull * 768 * 2));
    ushort_t* wqkvT = (ushort_t*)(ws + alloc(1536ull * 512 * 2));   // [wqT;wkT;wvT]
    ushort_t* ff0T  = (ushort_t*)(ws + alloc(512ull * 768 * 2));
    ushort_t* ff1T  = (ushort_t*)(ws + alloc(512ull * 512 * 2));
    float*    bcat  = (float*)   (ws + alloc(1536 * 4));
    size_t base_bytes = o;
    size_t ff2T_bytes = 49408ull * 512 * 2;                          // 50.6 MB
    bool use_ff2T = (ws_size >= base_bytes + ff2T_bytes + 256);
    ushort_t* ff2T = use_ff2T ? (ushort_t*)(ws + alloc(ff2T_bytes)) : nullptr;

    dim3 b32x8(32, 8);

    transpose_bf3<<<dim3(16, 16, 3), b32x8, 0, stream>>>(wq, wk, wv, wqkvT);
    transpose_bf<<<dim3(16, 24), b32x8, 0, stream>>>(ff0_w, ff0T, 768, 512);
    transpose_bf<<<dim3(16, 16), b32x8, 0, stream>>>(ff1_w, ff1T, 512, 512);
    biascat<<<6, 256, 0, stream>>>(wq_b, wk_b, wv_b, bcat);
    if (use_ff2T)
        transpose_ff2<<<dim3(772, 8), 256, 0, stream>>>(ff2_w, ff2T);
    conv_pad<<<(1664 * 768 + 255) / 256, 256, 0, stream>>>(img, Aimg, 1600, 768, 1664 * 768);

    // ff0: img_out = Aimg @ ff0T^T + ff0_b -> tmpf [1600][512]
    gemm_bf16<0, 0, 0><<<dim3(4, 13, 1), 256, 0, stream>>>(
        Aimg, ff0T, tmpf, nullptr, ff0_b, 768, 768, 768, 512, 0, 0, 0, 1600, 1.f);

    build_x<<<4096, 64, 0, stream>>>(tmpf, cap, tok, pos, ln_g, ln_b, x, xb);

    for (int l = 0; l < 2; l++) {
        // fused qkv: [4096][1536] = xb @ WqkvT^T + bcat   (wv_b included in V)
        gemm_bf16<0, 0, 0><<<dim3(12, 32, 1), 256, 0, stream>>>(
            xb, wqkvT, nullptr, qkvb, bcat, 512, 512, 512, 1536, 0, 0, 0, 4096, 1.f);
        // fused attention + residual-LN: writes x, xb directly
        attn_fused<<<dim3(2, 32), 512, 0, stream>>>(qkvb, x, xb, ln_g, ln_b);
        // fused ff1 + residual-LN: updates x, xb in place
        ff1_fused<<<126, 512, 0, stream>>>(xb, ff1T, ff1_b, x, ln_g, ln_b);
    }

    // logits (f32 out): d_out = gather(xb) @ ff2T^T + ff2_b
    if (use_ff2T) {
        gemm_big<<<dim3(193, 10), 512, 0, stream>>>(
            xb, ff2T, (float*)d_out, ff2_b, 512, 512, 49408, 2432);
    } else {
        gather_txt<<<(2560 * 512 + 255) / 256, 256, 0, stream>>>(xb, Atxt);
        gemm_bf16<1, 1, 0><<<dim3(386, 20, 1), 256, 0, stream>>>(
            Atxt, ff2_w, (float*)d_out, nullptr, ff2_b, 512, 512, 49408, 49408,
            0, 0, 0, 2432, 1.f);
    }
}